// Round 3
// baseline (455.178 us; speedup 1.0000x reference)
//
#include <hip/hip_runtime.h>

#define FDIM 128
#define LN_EPS 1e-5f
#define NBKT_SHIFT 8           // 256 nodes per bucket
#define BKT_NODES 256
#define MAXBKT 512             // supports N <= 131072
#define CAP_SHIFT 13           // 8192 edge capacity per bucket (mean 4096, ~64 sigma)
#define BKT_CAP 8192

typedef short bf16x8 __attribute__((ext_vector_type(8)));
typedef float f32x4 __attribute__((ext_vector_type(4)));
typedef float f32x2 __attribute__((ext_vector_type(2)));
typedef ushort u16x8 __attribute__((ext_vector_type(8)));
typedef unsigned long long u64;
typedef long long i64;

static __device__ __forceinline__ ushort f2bf(float f) {
    union { float f; unsigned u; } v; v.f = f;
    unsigned r = v.u + 0x7FFFu + ((v.u >> 16) & 1u);  // RNE
    return (ushort)(r >> 16);
}
static __device__ __forceinline__ float bf2f(ushort h) {
    union { unsigned u; float f; } v; v.u = ((unsigned)h) << 16;
    return v.f;
}
// fp8 e4m3 (OCP on gfx950) encode/decode via HW converts
static __device__ __forceinline__ unsigned char f2fp8(float f) {
    return (unsigned char)__builtin_amdgcn_cvt_pk_fp8_f32(f, f, 0u, false);
}
static __device__ __forceinline__ float fp8tof(unsigned char b) {
    f32x2 p = __builtin_amdgcn_cvt_pk_f32_fp8((unsigned)b, false);
    return p[0];
}
static __device__ __forceinline__ void fp8x8_add(uint2 w, f32x2* acc) {
    acc[0] += __builtin_amdgcn_cvt_pk_f32_fp8(w.x, false);
    acc[1] += __builtin_amdgcn_cvt_pk_f32_fp8(w.x, true);
    acc[2] += __builtin_amdgcn_cvt_pk_f32_fp8(w.y, false);
    acc[3] += __builtin_amdgcn_cvt_pk_f32_fp8(w.y, true);
}

// async global->LDS, 16 B per lane (wave-uniform LDS base + lane*16)
typedef __attribute__((address_space(3))) unsigned char lds_uchar;
typedef const __attribute__((address_space(1))) unsigned char glob_uchar;
static __device__ __forceinline__ void gload16(const unsigned char* g, unsigned char* l) {
    __builtin_amdgcn_global_load_lds((glob_uchar*)g, (lds_uchar*)l, 16, 0, 0);
}

// ---------------- bucketed edge scatter (fixed-capacity buckets) ----------------
// 4096 edges/block. Packs (src,local_dst) into one u32: src<<8 | (dst & 255).

__launch_bounds__(256)
__global__ void k_bkt_scatter(const int* __restrict__ src, const int* __restrict__ dst,
                              int* __restrict__ bcur, unsigned* __restrict__ bktA,
                              int E, int nbkt) {
    __shared__ int h[2][MAXBKT], lbase[2][MAXBKT], lcur[2][MAXBKT];
    const int t = threadIdx.x;
    const int half = t >> 7;
    for (int i = t; i < 2 * MAXBKT; i += 256) ((int*)h)[i] = 0;
    __syncthreads();
    const int E4 = E >> 2;   // E multiple of 4
    const int4* s4p = (const int4*)src;
    const int4* d4p = (const int4*)dst;
    int4 sv[4], dv[4]; bool ok[4];
#pragma unroll
    for (int r = 0; r < 4; r++) {
        int i4 = blockIdx.x * 1024 + r * 256 + t;
        ok[r] = (i4 < E4);
        if (ok[r]) {
            sv[r] = s4p[i4]; dv[r] = d4p[i4];
            atomicAdd(&h[half][dv[r].x >> NBKT_SHIFT], 1);
            atomicAdd(&h[half][dv[r].y >> NBKT_SHIFT], 1);
            atomicAdd(&h[half][dv[r].z >> NBKT_SHIFT], 1);
            atomicAdd(&h[half][dv[r].w >> NBKT_SHIFT], 1);
        }
    }
    __syncthreads();
    for (int i = t; i < 2 * nbkt; i += 256) {
        const int hh = (i >= nbkt) ? 1 : 0;
        const int b = hh ? (i - nbkt) : i;
        const int c = h[hh][b];
        lbase[hh][b] = c ? ((b << CAP_SHIFT) + atomicAdd(&bcur[b], c)) : 0;
        lcur[hh][b] = 0;
    }
    __syncthreads();
#pragma unroll
    for (int r = 0; r < 4; r++) {
        if (!ok[r]) continue;
        int ss[4] = {sv[r].x, sv[r].y, sv[r].z, sv[r].w};
        int dd[4] = {dv[r].x, dv[r].y, dv[r].z, dv[r].w};
#pragma unroll
        for (int j = 0; j < 4; j++) {
            int b = dd[j] >> NBKT_SHIFT;
            int p = atomicAdd(&lcur[half][b], 1);
            bktA[(size_t)lbase[half][b] + p] =
                ((unsigned)ss[j] << NBKT_SHIFT) | (unsigned)(dd[j] & (BKT_NODES - 1));
        }
    }
}

// merged per-bucket: degree count -> wave scan -> rowinfo/dinv -> LDS-sorted CSR fill
// Bucket CSR region (8192 x 4B = 32 KB) is sorted in LDS, then dumped coalesced.

__launch_bounds__(512)
__global__ void k_build(const unsigned* __restrict__ bktA, const int* __restrict__ bcur,
                        int2* __restrict__ rowinfo, float* __restrict__ dinv,
                        int* __restrict__ csr_src, int N) {
    __shared__ int sorted[BKT_CAP];      // 32 KB
    __shared__ int cnt[BKT_NODES];
    __shared__ int cur[BKT_NODES];
    __shared__ int wpart[4], wbase[4];
    const int t = threadIdx.x;
    const int b = blockIdx.x;
    const int nb = b << NBKT_SHIFT;
    if (t < BKT_NODES) cnt[t] = 0;
    __syncthreads();
    const int beg = b << CAP_SHIFT;
    const int tot = bcur[b];
    // pass 1: histogram (coalesced global read)
    for (int i = t; i < tot; i += 512)
        atomicAdd(&cnt[bktA[beg + i] & (BKT_NODES - 1)], 1);
    __syncthreads();
    // scan over 256 counters (4 waves)
    const int lane = t & 63, wv = t >> 6;
    int my = 0, x = 0;
    if (t < BKT_NODES) {
        my = cnt[t];
        x = my;
#pragma unroll
        for (int off = 1; off < 64; off <<= 1) {
            int y = __shfl_up(x, off, 64);
            if (lane >= off) x += y;
        }
        if (lane == 63) wpart[wv] = x;
    }
    __syncthreads();
    if (t == 0) {
        int s = 0;
        for (int w = 0; w < 4; w++) { int tmp = wpart[w]; wbase[w] = s; s += tmp; }
    }
    __syncthreads();
    if (t < BKT_NODES) {
        const int incl = x + wbase[wv];
        const int rbeg = incl - my;          // local exclusive prefix
        cur[t] = rbeg;
        const int n = nb + t;
        if (n < N) {
            rowinfo[n] = make_int2(beg + rbeg, my);
            dinv[n] = rsqrtf((float)(my + 1));  // +1 self-loop
        }
    }
    __syncthreads();
    // pass 2: scatter into LDS (global re-read is L2-hot), then coalesced dump
    for (int i = t; i < tot; i += 512) {
        unsigned pr = bktA[beg + i];
        int d = pr & (BKT_NODES - 1);
        int p = atomicAdd(&cur[d], 1);
        sorted[p] = (int)(pr >> NBKT_SHIFT);
    }
    __syncthreads();
    for (int i = t; i < tot; i += 512)
        csr_src[beg + i] = sorted[i];
}

// ---------------- W prep: layer0 -> bf16 Wt_b[n][k]; layers 1,2 -> fp8 Wt8 ----------------
// Also zeroes gsums and bcur (replaces a memset dispatch; runs before scatter).

__global__ void k_prep_w(const float* __restrict__ Wa, const float* __restrict__ Wb,
                         const float* __restrict__ Wc, ushort* __restrict__ Wt_b,
                         unsigned char* __restrict__ Wt8, float* __restrict__ gsums,
                         int* __restrict__ bcur) {
    int idx = blockIdx.x * 256 + threadIdx.x;  // 192*256 = 49152 = 3*16384
    int layer = idx >> 14;
    int r = idx & 16383;
    int nn = r >> 7, kk = r & 127;
    if (layer == 0) {
        Wt_b[r] = f2bf(Wa[kk * 128 + nn]);
    } else {
        const float* W = (layer == 1) ? Wb : Wc;
        Wt8[(size_t)(layer - 1) * 16384 + r] = f2fp8(W[kk * 128 + nn]);
    }
    if (idx < 8192) gsums[idx] = 0.f;
    if (idx < MAXBKT) bcur[idx] = 0;
}

// ---------------- layer-1 MFMA GEMM (bf16): xs(fp8) = dinv .* (X_f32 @ W) ----------------

__launch_bounds__(256)
__global__ void k_gemm_f32(const float* __restrict__ X, const ushort* __restrict__ Wt,
                           const float* __restrict__ dinv, unsigned char* __restrict__ C,
                           int N) {
    __shared__ __align__(16) ushort As[128][136];
    __shared__ ushort Ws[128][136];
    const int t = threadIdx.x;
    const int row0 = blockIdx.x * 128;

#pragma unroll
    for (int i = 0; i < 8; i++) {
        int c = t + i * 256;
        int r = c >> 4, c8 = (c & 15) * 8;
        *(bf16x8*)&Ws[r][c8] = *(const bf16x8*)&Wt[r * 128 + c8];
    }
#pragma unroll
    for (int i = 0; i < 8; i++) {
        int c = t + i * 256;
        int r = c >> 4, c8 = (c & 15) * 8;
        int row = row0 + r;
        bf16x8 pk = {0, 0, 0, 0, 0, 0, 0, 0};
        if (row < N) {
            const float* sp = X + (size_t)row * FDIM + c8;
            float4 u0 = *(const float4*)(sp);
            float4 u1 = *(const float4*)(sp + 4);
            pk[0] = (short)f2bf(u0.x); pk[1] = (short)f2bf(u0.y);
            pk[2] = (short)f2bf(u0.z); pk[3] = (short)f2bf(u0.w);
            pk[4] = (short)f2bf(u1.x); pk[5] = (short)f2bf(u1.y);
            pk[6] = (short)f2bf(u1.z); pk[7] = (short)f2bf(u1.w);
        }
        *(bf16x8*)&As[r][c8] = pk;
    }
    __syncthreads();

    const int w = t >> 6, l = t & 63;
    const int m = l & 15, q = l >> 4;
    const int r0 = w * 32;

    bf16x8 a0[4], a1[4];
#pragma unroll
    for (int ks = 0; ks < 4; ks++) {
        a0[ks] = *(const bf16x8*)&As[r0 + m][ks * 32 + q * 8];
        a1[ks] = *(const bf16x8*)&As[r0 + 16 + m][ks * 32 + q * 8];
    }

    f32x4 acc0[8], acc1[8];
#pragma unroll
    for (int ct = 0; ct < 8; ct++) { acc0[ct] = {0, 0, 0, 0}; acc1[ct] = {0, 0, 0, 0}; }

#pragma unroll
    for (int ct = 0; ct < 8; ct++) {
#pragma unroll
        for (int ks = 0; ks < 4; ks++) {
            bf16x8 b = *(const bf16x8*)&Ws[ct * 16 + m][ks * 32 + q * 8];
            acc0[ct] = __builtin_amdgcn_mfma_f32_16x16x32_bf16(a0[ks], b, acc0[ct], 0, 0, 0);
            acc1[ct] = __builtin_amdgcn_mfma_f32_16x16x32_bf16(a1[ks], b, acc1[ct], 0, 0, 0);
        }
    }

    float dv0[4], dv1[4];
#pragma unroll
    for (int r = 0; r < 4; r++) {
        int row = row0 + r0 + q * 4 + r;
        dv0[r] = (row < N) ? dinv[row] : 0.f;
        dv1[r] = (row + 16 < N) ? dinv[row + 16] : 0.f;
    }

    // stage fp8 tile into LDS (reuse As), then coalesced 16-B stores
    __syncthreads();
    char* Ab = (char*)&As[0][0];
#pragma unroll
    for (int ct = 0; ct < 8; ct++) {
#pragma unroll
        for (int r = 0; r < 4; r++) {
            int rl = r0 + q * 4 + r;
            Ab[rl * 128 + ct * 16 + m] = (char)f2fp8(acc0[ct][r] * dv0[r]);
            Ab[(rl + 16) * 128 + ct * 16 + m] = (char)f2fp8(acc1[ct][r] * dv1[r]);
        }
    }
    __syncthreads();
    const uint4* As4 = (const uint4*)Ab;
#pragma unroll
    for (int i = 0; i < 4; i++) {
        int c = t + i * 256;
        int row = c >> 3;
        int col = (c & 7) * 16;
        int grow = row0 + row;
        if (grow < N) *(uint4*)&C[(size_t)grow * FDIM + col] = As4[c];
    }
}

// ---------------- layers 2/3 MFMA GEMM (fp8 x fp8): xs(fp8) = dinv .* (A_fp8 @ W_fp8) ----
// A/W tiles staged via async global_load_lds (16 B/lane), linear LDS layout.

__launch_bounds__(256)
__global__ void k_gemm_fp8(const unsigned char* __restrict__ X,
                           const unsigned char* __restrict__ W8,
                           const float* __restrict__ dinv, unsigned char* __restrict__ C,
                           int N) {
    __shared__ __align__(16) unsigned char As[128 * 128];
    __shared__ __align__(16) unsigned char Ws[128 * 128];
    const int t = threadIdx.x;
    const int w = t >> 6, l = t & 63;
    const int row0 = blockIdx.x * 128;

    // async stage: each wave covers rows w*32 .. w*32+31 of both tiles (4 iters x 8 rows).
    // NOTE: per-lane GLOBAL addr, wave-uniform LDS base + lane*16 (linear layout required).
    {
        const int lrow = (l >> 3);           // 0..7 row within 8-row chunk
        const int lcol = (l & 7) * 16;       // 16-B column slice
        const unsigned char* gx = X + (size_t)(row0 + w * 32 + lrow) * FDIM + lcol;
        const unsigned char* gw = W8 + (size_t)(w * 32 + lrow) * FDIM + lcol;
#pragma unroll
        for (int i = 0; i < 4; i++) {
            gload16(gx + (size_t)i * 8 * FDIM, &As[(w * 32 + i * 8) * FDIM]);
            gload16(gw + (size_t)i * 8 * FDIM, &Ws[(w * 32 + i * 8) * FDIM]);
        }
    }
    __syncthreads();   // drains vmcnt (incl. global_load_lds) before LDS reads

    const int m = l & 15, q = l >> 4;
    const int r0 = w * 32;

    i64 a0[4], a1[4];
#pragma unroll
    for (int ks = 0; ks < 4; ks++) {
        a0[ks] = *(const i64*)&As[(r0 + m) * FDIM + ks * 32 + q * 8];
        a1[ks] = *(const i64*)&As[(r0 + 16 + m) * FDIM + ks * 32 + q * 8];
    }

    f32x4 acc0[8], acc1[8];
#pragma unroll
    for (int ct = 0; ct < 8; ct++) { acc0[ct] = {0, 0, 0, 0}; acc1[ct] = {0, 0, 0, 0}; }

#pragma unroll
    for (int ct = 0; ct < 8; ct++) {
#pragma unroll
        for (int ks = 0; ks < 4; ks++) {
            i64 b = *(const i64*)&Ws[(ct * 16 + m) * FDIM + ks * 32 + q * 8];
            acc0[ct] = __builtin_amdgcn_mfma_f32_16x16x32_fp8_fp8(a0[ks], b, acc0[ct], 0, 0, 0);
            acc1[ct] = __builtin_amdgcn_mfma_f32_16x16x32_fp8_fp8(a1[ks], b, acc1[ct], 0, 0, 0);
        }
    }

    float dv0[4], dv1[4];
#pragma unroll
    for (int r = 0; r < 4; r++) {
        int row = row0 + r0 + q * 4 + r;
        dv0[r] = (row < N) ? dinv[row] : 0.f;
        dv1[r] = (row + 16 < N) ? dinv[row + 16] : 0.f;
    }

    __syncthreads();
    char* Ab = (char*)&As[0];
#pragma unroll
    for (int ct = 0; ct < 8; ct++) {
#pragma unroll
        for (int r = 0; r < 4; r++) {
            int rl = r0 + q * 4 + r;
            Ab[rl * 128 + ct * 16 + m] = (char)f2fp8(acc0[ct][r] * dv0[r]);
            Ab[(rl + 16) * 128 + ct * 16 + m] = (char)f2fp8(acc1[ct][r] * dv1[r]);
        }
    }
    __syncthreads();
    const uint4* As4 = (const uint4*)Ab;
#pragma unroll
    for (int i = 0; i < 4; i++) {
        int c = t + i * 256;
        int row = c >> 3;
        int col = (c & 7) * 16;
        int grow = row0 + row;
        if (grow < N) *(uint4*)&C[(size_t)grow * FDIM + col] = As4[c];
    }
}

// ---------------- fused pull-aggregate, one node per wave64, fp8 in / fp8 out ----------------
// R11 inner loop (proven): 4 row-groups x 16 lanes, 512-B gathers, 2-deep prefetch,
// 32-bit saddr-form gathers. fuse_pool: layer-3 mode — skip fp8 store, accumulate
// per-graph sums (mean-pool input) in LDS, flush once per block.

__launch_bounds__(256)
__global__ void k_aggregate(const unsigned char* __restrict__ xs8,
                            const int2* __restrict__ rowinfo,
                            const int* __restrict__ csr_src, const float* __restrict__ dinv,
                            const float* __restrict__ bias, unsigned char* __restrict__ out,
                            const int* __restrict__ batch, float* __restrict__ gsums,
                            int N, int do_relu, int fuse_pool) {
    __shared__ float gsum_s[FDIM];
    __shared__ int gb_s[4];
    const int t = threadIdx.x;
    const int n = (blockIdx.x << 2) + (t >> 6);
    const bool active = (n < N);
    const int l = t & 63;
    const int fl = l & 15;      // feature slot: features fl*8 .. fl*8+7
    const int grp = l >> 4;     // row group 0..3
    const unsigned foff = (unsigned)fl << 3;   // byte offset within a 128-B row

    if (fuse_pool) {
        if (t < FDIM) gsum_s[t] = 0.f;
        if (t < 4) {
            int nn = (blockIdx.x << 2) + t;
            gb_s[t] = batch[nn < N ? nn : (N - 1)];
        }
        __syncthreads();
    }

    f32x2 acc[4] = {{0, 0}, {0, 0}, {0, 0}, {0, 0}};
    if (active && grp == 0) {
        uint2 sv = *(const uint2*)(xs8 + (((unsigned)n << 7) | foff));
        fp8x8_add(sv, acc);
    }

    const int2 ri = active ? rowinfo[n] : make_int2(0, 0);
    const int beg = ri.x;
    const int deg = ri.y;

    for (int base = 0; base < deg; base += 64) {
        const int m = min(64, deg - base);
        int idx = 0;
        if (l < m) idx = csr_src[(unsigned)(beg + base + l)];  // coalesced
        int j = grp;
        if (j < m) {
            int s0 = __shfl(idx, j, 64);
            uint2 v0 = *(const uint2*)(xs8 + (((unsigned)s0 << 7) | foff));
            int j2 = j + 4;
            if (j2 < m) {
                int s1 = __shfl(idx, j2, 64);
                uint2 v1 = *(const uint2*)(xs8 + (((unsigned)s1 << 7) | foff));
                for (j = j2 + 4; j < m; j += 4) {
                    int s2 = __shfl(idx, j, 64);
                    uint2 v2 = *(const uint2*)(xs8 + (((unsigned)s2 << 7) | foff));
                    fp8x8_add(v0, acc);
                    v0 = v1; v1 = v2;
                }
                fp8x8_add(v0, acc);
                fp8x8_add(v1, acc);
            } else {
                fp8x8_add(v0, acc);
            }
        }
    }

    float a[8] = {acc[0][0], acc[0][1], acc[1][0], acc[1][1],
                  acc[2][0], acc[2][1], acc[3][0], acc[3][1]};
#pragma unroll
    for (int k = 0; k < 8; k++) {
        a[k] += __shfl_xor(a[k], 16, 64);
        a[k] += __shfl_xor(a[k], 32, 64);
    }

    if (active && grp == 0) {
        const float d = dinv[n];
        const float4 b0 = ((const float4*)bias)[fl * 2];
        const float4 b1 = ((const float4*)bias)[fl * 2 + 1];
        const float bb[8] = {b0.x, b0.y, b0.z, b0.w, b1.x, b1.y, b1.z, b1.w};
        float v[8];
#pragma unroll
        for (int k = 0; k < 8; k++) {
            v[k] = d * a[k] + bb[k];
            if (do_relu) v[k] = fmaxf(v[k], 0.f);
        }
        if (!fuse_pool) {
            uint2 o;
            unsigned d0 = __builtin_amdgcn_cvt_pk_fp8_f32(v[0], v[1], 0u, false);
            o.x = __builtin_amdgcn_cvt_pk_fp8_f32(v[2], v[3], d0, true);
            unsigned d1 = __builtin_amdgcn_cvt_pk_fp8_f32(v[4], v[5], 0u, false);
            o.y = __builtin_amdgcn_cvt_pk_fp8_f32(v[6], v[7], d1, true);
            ((uint2*)out)[(size_t)n * 16 + fl] = o;
        } else {
            const bool uni = (gb_s[0] == gb_s[3]);   // batch sorted -> all 4 equal
            if (uni) {
#pragma unroll
                for (int k = 0; k < 8; k++) atomicAdd(&gsum_s[foff + k], v[k]);
            } else {
                const int g = gb_s[t >> 6];
#pragma unroll
                for (int k = 0; k < 8; k++) atomicAdd(&gsums[g * FDIM + foff + k], v[k]);
            }
        }
    }
    if (fuse_pool) {
        __syncthreads();
        if (gb_s[0] == gb_s[3] && t < FDIM) atomicAdd(&gsums[gb_s[0] * FDIM + t], gsum_s[t]);
    }
}

// ---------------- per-graph mean + MLP + LayerNorm ----------------

__launch_bounds__(128)
__global__ void k_final(const float* __restrict__ sums, const int* __restrict__ batch, int N,
                        const float* __restrict__ Wm1, const float* __restrict__ bm1,
                        const float* __restrict__ Wm2, const float* __restrict__ bm2,
                        const float* __restrict__ ln_g, const float* __restrict__ ln_b,
                        float* __restrict__ out) {
    const int g = blockIdx.x;
    const int t = threadIdx.x;

    int lo = 0, hi = N;
    while (lo < hi) { int mid = (lo + hi) >> 1; if (batch[mid] < g) lo = mid + 1; else hi = mid; }
    int lo2 = lo, hi2 = N;
    while (lo2 < hi2) { int mid = (lo2 + hi2) >> 1; if (batch[mid] < g + 1) lo2 = mid + 1; else hi2 = mid; }
    float cnt = (float)(lo2 - lo);

    float gl = sums[g * FDIM + t] / fmaxf(cnt, 1.0f);

    __shared__ float gbuf[FDIM];
    __shared__ float hbuf[FDIM];
    __shared__ float wsum[4];
    gbuf[t] = gl;
    __syncthreads();

    float h = bm1[t];
#pragma unroll 8
    for (int k = 0; k < FDIM; k++) h += gbuf[k] * Wm1[k * FDIM + t];
    h = fmaxf(h, 0.f);
    hbuf[t] = h;
    __syncthreads();

    float y = bm2[t];
#pragma unroll 8
    for (int k = 0; k < FDIM; k++) y += hbuf[k] * Wm2[k * FDIM + t];

    float s = y, s2 = y * y;
#pragma unroll
    for (int off = 32; off > 0; off >>= 1) {
        s += __shfl_down(s, off, 64);
        s2 += __shfl_down(s2, off, 64);
    }
    if ((t & 63) == 0) { wsum[t >> 6] = s; wsum[2 + (t >> 6)] = s2; }
    __syncthreads();
    float sum = wsum[0] + wsum[1];
    float sumsq = wsum[2] + wsum[3];
    float mu = sum * (1.0f / FDIM);
    float var = sumsq * (1.0f / FDIM) - mu * mu;
    float r = rsqrtf(var + LN_EPS);
    out[g * FDIM + t] = (y - mu) * r * ln_g[t] + ln_b[t];
}

// ---------------- launch ----------------

extern "C" void kernel_launch(void* const* d_in, const int* in_sizes, int n_in,
                              void* d_out, int out_size, void* d_ws, size_t ws_size,
                              hipStream_t stream) {
    const float* x_in  = (const float*)d_in[0];
    const int*   eidx  = (const int*)d_in[1];
    const int*   batch = (const int*)d_in[2];
    const float* W1 = (const float*)d_in[3];
    const float* b1 = (const float*)d_in[4];
    const float* W2 = (const float*)d_in[5];
    const float* b2 = (const float*)d_in[6];
    const float* W3 = (const float*)d_in[7];
    const float* b3 = (const float*)d_in[8];
    const float* Wm1 = (const float*)d_in[9];
    const float* bm1 = (const float*)d_in[10];
    const float* Wm2 = (const float*)d_in[11];
    const float* bm2 = (const float*)d_in[12];
    const float* ln_g = (const float*)d_in[13];
    const float* ln_b = (const float*)d_in[14];
    float* out = (float*)d_out;

    const int N = in_sizes[0] / FDIM;   // 100000
    const int E = in_sizes[1] / 2;      // 1600000
    const int G = out_size / FDIM;      // 64

    const int* src = eidx;
    const int* dst = eidx + E;

    const int nbkt = (N + BKT_NODES - 1) >> NBKT_SHIFT;        // 391

    // workspace layout
    char* p = (char*)d_ws;
    unsigned* bktA = (unsigned*)p;    p += (size_t)nbkt * BKT_CAP * 4;   // 12.8 MB (packed)
    unsigned char* B0q = (unsigned char*)p; p += (size_t)N * FDIM;       // 12.8 MB (fp8 xs)
    unsigned char* B1q = (unsigned char*)p; p += (size_t)N * FDIM;       // 12.8 MB (fp8 agg)
    int* csr_src = (int*)p;           p += (size_t)nbkt * BKT_CAP * 4;   // 12.8 MB
    int2* rowinfo = (int2*)p;         p += (size_t)N * 8;
    float* dinv = (float*)p;          p += (size_t)N * 4;
    ushort* Wt_b = (ushort*)p;        p += 16384 * 2;
    unsigned char* Wt8 = (unsigned char*)p; p += 2 * 16384;
    float* gsums = (float*)p;         p += (size_t)G * FDIM * 4;
    int* bcur = (int*)p;              p += MAXBKT * 4;

    const int TPB = 256;
    dim3 blk(TPB);
    dim3 gAgg((N + 3) / 4);
    dim3 gTile((N + 127) / 128);
    const int nEb = (E + 4095) / 4096;

    // ---- prep (also zeroes gsums/bcur) + build ----
    k_prep_w<<<dim3(192), blk, 0, stream>>>(W1, W2, W3, Wt_b, Wt8, gsums, bcur);
    k_bkt_scatter<<<dim3(nEb), blk, 0, stream>>>(src, dst, bcur, bktA, E, nbkt);
    k_build<<<dim3(nbkt), dim3(512), 0, stream>>>(bktA, bcur, rowinfo, dinv, csr_src, N);

    // ---- layer 1 (fp32 input, bf16 MFMA) ----
    k_gemm_f32<<<gTile, blk, 0, stream>>>(x_in, Wt_b, dinv, B0q, N);
    k_aggregate<<<gAgg, blk, 0, stream>>>(B0q, rowinfo, csr_src, dinv, b1, B1q,
                                          batch, gsums, N, 1, 0);

    // ---- layer 2 (fp8 MFMA) ----
    k_gemm_fp8<<<gTile, blk, 0, stream>>>(B1q, Wt8, dinv, B0q, N);
    k_aggregate<<<gAgg, blk, 0, stream>>>(B0q, rowinfo, csr_src, dinv, b2, B1q,
                                          batch, gsums, N, 1, 0);

    // ---- layer 3 (fp8 MFMA, no relu, fused mean-pool accumulate) ----
    k_gemm_fp8<<<gTile, blk, 0, stream>>>(B1q, Wt8 + 16384, dinv, B0q, N);
    k_aggregate<<<gAgg, blk, 0, stream>>>(B0q, rowinfo, csr_src, dinv, b3, B1q,
                                          batch, gsums, N, 0, 1);

    // ---- MLP + LN ----
    k_final<<<dim3(G), dim3(FDIM), 0, stream>>>(gsums, batch, N, Wm1, bm1, Wm2, bm2,
                                                ln_g, ln_b, out);
}

// Round 4
// 388.455 us; speedup vs baseline: 1.1718x; 1.1718x over previous
//
#include <hip/hip_runtime.h>

#define FDIM 128
#define LN_EPS 1e-5f
#define NBKT_SHIFT 8           // 256 nodes per bucket
#define BKT_NODES 256
#define MAXBKT 512             // supports N <= 131072
#define CAP_SHIFT 13           // 8192 edge capacity per bucket (mean 4096, ~64 sigma)
#define BKT_CAP 8192

typedef short bf16x8 __attribute__((ext_vector_type(8)));
typedef float f32x4 __attribute__((ext_vector_type(4)));
typedef float f32x2 __attribute__((ext_vector_type(2)));
typedef ushort u16x8 __attribute__((ext_vector_type(8)));
typedef unsigned long long u64;
typedef long long i64;

static __device__ __forceinline__ ushort f2bf(float f) {
    union { float f; unsigned u; } v; v.f = f;
    unsigned r = v.u + 0x7FFFu + ((v.u >> 16) & 1u);  // RNE
    return (ushort)(r >> 16);
}
static __device__ __forceinline__ float bf2f(ushort h) {
    union { unsigned u; float f; } v; v.u = ((unsigned)h) << 16;
    return v.f;
}
// fp8 e4m3 (OCP on gfx950) encode/decode via HW converts
static __device__ __forceinline__ unsigned char f2fp8(float f) {
    return (unsigned char)__builtin_amdgcn_cvt_pk_fp8_f32(f, f, 0u, false);
}
static __device__ __forceinline__ float fp8tof(unsigned char b) {
    f32x2 p = __builtin_amdgcn_cvt_pk_f32_fp8((unsigned)b, false);
    return p[0];
}
static __device__ __forceinline__ void fp8x8_add(uint2 w, f32x2* acc) {
    acc[0] += __builtin_amdgcn_cvt_pk_f32_fp8(w.x, false);
    acc[1] += __builtin_amdgcn_cvt_pk_f32_fp8(w.x, true);
    acc[2] += __builtin_amdgcn_cvt_pk_f32_fp8(w.y, false);
    acc[3] += __builtin_amdgcn_cvt_pk_f32_fp8(w.y, true);
}

// async global->LDS, 16 B per lane (wave-uniform LDS base + lane*16)
typedef __attribute__((address_space(3))) unsigned char lds_uchar;
typedef const __attribute__((address_space(1))) unsigned char glob_uchar;
static __device__ __forceinline__ void gload16(const unsigned char* g, unsigned char* l) {
    __builtin_amdgcn_global_load_lds((glob_uchar*)g, (lds_uchar*)l, 16, 0, 0);
}

// ---------------- bucketed edge scatter (fixed-capacity buckets) ----------------
// 4096 edges/block. Packs (src,local_dst) into one u32: src<<8 | (dst & 255).

__launch_bounds__(256)
__global__ void k_bkt_scatter(const int* __restrict__ src, const int* __restrict__ dst,
                              int* __restrict__ bcur, unsigned* __restrict__ bktA,
                              int E, int nbkt) {
    __shared__ int h[2][MAXBKT], lbase[2][MAXBKT], lcur[2][MAXBKT];
    const int t = threadIdx.x;
    const int half = t >> 7;
    for (int i = t; i < 2 * MAXBKT; i += 256) ((int*)h)[i] = 0;
    __syncthreads();
    const int E4 = E >> 2;   // E multiple of 4
    const int4* s4p = (const int4*)src;
    const int4* d4p = (const int4*)dst;
    int4 sv[4], dv[4]; bool ok[4];
#pragma unroll
    for (int r = 0; r < 4; r++) {
        int i4 = blockIdx.x * 1024 + r * 256 + t;
        ok[r] = (i4 < E4);
        if (ok[r]) {
            sv[r] = s4p[i4]; dv[r] = d4p[i4];
            atomicAdd(&h[half][dv[r].x >> NBKT_SHIFT], 1);
            atomicAdd(&h[half][dv[r].y >> NBKT_SHIFT], 1);
            atomicAdd(&h[half][dv[r].z >> NBKT_SHIFT], 1);
            atomicAdd(&h[half][dv[r].w >> NBKT_SHIFT], 1);
        }
    }
    __syncthreads();
    for (int i = t; i < 2 * nbkt; i += 256) {
        const int hh = (i >= nbkt) ? 1 : 0;
        const int b = hh ? (i - nbkt) : i;
        const int c = h[hh][b];
        lbase[hh][b] = c ? ((b << CAP_SHIFT) + atomicAdd(&bcur[b], c)) : 0;
        lcur[hh][b] = 0;
    }
    __syncthreads();
#pragma unroll
    for (int r = 0; r < 4; r++) {
        if (!ok[r]) continue;
        int ss[4] = {sv[r].x, sv[r].y, sv[r].z, sv[r].w};
        int dd[4] = {dv[r].x, dv[r].y, dv[r].z, dv[r].w};
#pragma unroll
        for (int j = 0; j < 4; j++) {
            int b = dd[j] >> NBKT_SHIFT;
            int p = atomicAdd(&lcur[half][b], 1);
            bktA[(size_t)lbase[half][b] + p] =
                ((unsigned)ss[j] << NBKT_SHIFT) | (unsigned)(dd[j] & (BKT_NODES - 1));
        }
    }
}

// merged per-bucket: degree count -> wave scan -> rowinfo/dinv -> LDS-sorted CSR fill
// Bucket CSR region (8192 x 4B = 32 KB) is sorted in LDS, then dumped coalesced.

__launch_bounds__(512)
__global__ void k_build(const unsigned* __restrict__ bktA, const int* __restrict__ bcur,
                        int2* __restrict__ rowinfo, float* __restrict__ dinv,
                        int* __restrict__ csr_src, int N) {
    __shared__ int sorted[BKT_CAP];      // 32 KB
    __shared__ int cnt[BKT_NODES];
    __shared__ int cur[BKT_NODES];
    __shared__ int wpart[4], wbase[4];
    const int t = threadIdx.x;
    const int b = blockIdx.x;
    const int nb = b << NBKT_SHIFT;
    if (t < BKT_NODES) cnt[t] = 0;
    __syncthreads();
    const int beg = b << CAP_SHIFT;
    const int tot = bcur[b];
    // pass 1: histogram (coalesced global read)
    for (int i = t; i < tot; i += 512)
        atomicAdd(&cnt[bktA[beg + i] & (BKT_NODES - 1)], 1);
    __syncthreads();
    // scan over 256 counters (4 waves)
    const int lane = t & 63, wv = t >> 6;
    int my = 0, x = 0;
    if (t < BKT_NODES) {
        my = cnt[t];
        x = my;
#pragma unroll
        for (int off = 1; off < 64; off <<= 1) {
            int y = __shfl_up(x, off, 64);
            if (lane >= off) x += y;
        }
        if (lane == 63) wpart[wv] = x;
    }
    __syncthreads();
    if (t == 0) {
        int s = 0;
        for (int w = 0; w < 4; w++) { int tmp = wpart[w]; wbase[w] = s; s += tmp; }
    }
    __syncthreads();
    if (t < BKT_NODES) {
        const int incl = x + wbase[wv];
        const int rbeg = incl - my;          // local exclusive prefix
        cur[t] = rbeg;
        const int n = nb + t;
        if (n < N) {
            rowinfo[n] = make_int2(beg + rbeg, my);
            dinv[n] = rsqrtf((float)(my + 1));  // +1 self-loop
        }
    }
    __syncthreads();
    // pass 2: scatter into LDS (global re-read is L2-hot), then coalesced dump
    for (int i = t; i < tot; i += 512) {
        unsigned pr = bktA[beg + i];
        int d = pr & (BKT_NODES - 1);
        int p = atomicAdd(&cur[d], 1);
        sorted[p] = (int)(pr >> NBKT_SHIFT);
    }
    __syncthreads();
    for (int i = t; i < tot; i += 512)
        csr_src[beg + i] = sorted[i];
}

// ---------------- W prep: layer0 -> bf16 Wt_b[n][k]; layers 1,2 -> fp8 Wt8 ----------------
// Also zeroes gsums and bcur (replaces a memset dispatch; runs before scatter).

__global__ void k_prep_w(const float* __restrict__ Wa, const float* __restrict__ Wb,
                         const float* __restrict__ Wc, ushort* __restrict__ Wt_b,
                         unsigned char* __restrict__ Wt8, float* __restrict__ gsums,
                         int* __restrict__ bcur) {
    int idx = blockIdx.x * 256 + threadIdx.x;  // 192*256 = 49152 = 3*16384
    int layer = idx >> 14;
    int r = idx & 16383;
    int nn = r >> 7, kk = r & 127;
    if (layer == 0) {
        Wt_b[r] = f2bf(Wa[kk * 128 + nn]);
    } else {
        const float* W = (layer == 1) ? Wb : Wc;
        Wt8[(size_t)(layer - 1) * 16384 + r] = f2fp8(W[kk * 128 + nn]);
    }
    if (idx < 8192) gsums[idx] = 0.f;
    if (idx < MAXBKT) bcur[idx] = 0;
}

// ---------------- layer-1 MFMA GEMM (bf16): xs(fp8) = dinv .* (X_f32 @ W) ----------------

__launch_bounds__(256)
__global__ void k_gemm_f32(const float* __restrict__ X, const ushort* __restrict__ Wt,
                           const float* __restrict__ dinv, unsigned char* __restrict__ C,
                           int N) {
    __shared__ __align__(16) ushort As[128][136];
    __shared__ ushort Ws[128][136];
    const int t = threadIdx.x;
    const int row0 = blockIdx.x * 128;

#pragma unroll
    for (int i = 0; i < 8; i++) {
        int c = t + i * 256;
        int r = c >> 4, c8 = (c & 15) * 8;
        *(bf16x8*)&Ws[r][c8] = *(const bf16x8*)&Wt[r * 128 + c8];
    }
#pragma unroll
    for (int i = 0; i < 8; i++) {
        int c = t + i * 256;
        int r = c >> 4, c8 = (c & 15) * 8;
        int row = row0 + r;
        bf16x8 pk = {0, 0, 0, 0, 0, 0, 0, 0};
        if (row < N) {
            const float* sp = X + (size_t)row * FDIM + c8;
            float4 u0 = *(const float4*)(sp);
            float4 u1 = *(const float4*)(sp + 4);
            pk[0] = (short)f2bf(u0.x); pk[1] = (short)f2bf(u0.y);
            pk[2] = (short)f2bf(u0.z); pk[3] = (short)f2bf(u0.w);
            pk[4] = (short)f2bf(u1.x); pk[5] = (short)f2bf(u1.y);
            pk[6] = (short)f2bf(u1.z); pk[7] = (short)f2bf(u1.w);
        }
        *(bf16x8*)&As[r][c8] = pk;
    }
    __syncthreads();

    const int w = t >> 6, l = t & 63;
    const int m = l & 15, q = l >> 4;
    const int r0 = w * 32;

    bf16x8 a0[4], a1[4];
#pragma unroll
    for (int ks = 0; ks < 4; ks++) {
        a0[ks] = *(const bf16x8*)&As[r0 + m][ks * 32 + q * 8];
        a1[ks] = *(const bf16x8*)&As[r0 + 16 + m][ks * 32 + q * 8];
    }

    f32x4 acc0[8], acc1[8];
#pragma unroll
    for (int ct = 0; ct < 8; ct++) { acc0[ct] = {0, 0, 0, 0}; acc1[ct] = {0, 0, 0, 0}; }

#pragma unroll
    for (int ct = 0; ct < 8; ct++) {
#pragma unroll
        for (int ks = 0; ks < 4; ks++) {
            bf16x8 b = *(const bf16x8*)&Ws[ct * 16 + m][ks * 32 + q * 8];
            acc0[ct] = __builtin_amdgcn_mfma_f32_16x16x32_bf16(a0[ks], b, acc0[ct], 0, 0, 0);
            acc1[ct] = __builtin_amdgcn_mfma_f32_16x16x32_bf16(a1[ks], b, acc1[ct], 0, 0, 0);
        }
    }

    float dv0[4], dv1[4];
#pragma unroll
    for (int r = 0; r < 4; r++) {
        int row = row0 + r0 + q * 4 + r;
        dv0[r] = (row < N) ? dinv[row] : 0.f;
        dv1[r] = (row + 16 < N) ? dinv[row + 16] : 0.f;
    }

    // stage fp8 tile into LDS (reuse As), then coalesced 16-B stores
    __syncthreads();
    char* Ab = (char*)&As[0][0];
#pragma unroll
    for (int ct = 0; ct < 8; ct++) {
#pragma unroll
        for (int r = 0; r < 4; r++) {
            int rl = r0 + q * 4 + r;
            Ab[rl * 128 + ct * 16 + m] = (char)f2fp8(acc0[ct][r] * dv0[r]);
            Ab[(rl + 16) * 128 + ct * 16 + m] = (char)f2fp8(acc1[ct][r] * dv1[r]);
        }
    }
    __syncthreads();
    const uint4* As4 = (const uint4*)Ab;
#pragma unroll
    for (int i = 0; i < 4; i++) {
        int c = t + i * 256;
        int row = c >> 3;
        int col = (c & 7) * 16;
        int grow = row0 + row;
        if (grow < N) *(uint4*)&C[(size_t)grow * FDIM + col] = As4[c];
    }
}

// ---------------- layers 2/3 MFMA GEMM (fp8 x fp8): xs(fp8) = dinv .* (A_fp8 @ W_fp8) ----
// A/W tiles staged via async global_load_lds (16 B/lane) with both-sides XOR swizzle:
// global source column pre-swizzled (col = 16*((l&7)^(l>>3))), LDS linear, reads XOR
// ((row&7)<<4). Read bank = (ks*8+q*2)^((m&7)<<2): 4 lanes/bank (parity with +16 pad).

__launch_bounds__(256)
__global__ void k_gemm_fp8(const unsigned char* __restrict__ X,
                           const unsigned char* __restrict__ W8,
                           const float* __restrict__ dinv, unsigned char* __restrict__ C,
                           int N) {
    __shared__ __align__(16) unsigned char As[128 * 128];
    __shared__ __align__(16) unsigned char Ws[128 * 128];
    const int t = threadIdx.x;
    const int w = t >> 6, l = t & 63;
    const int row0 = blockIdx.x * 128;

    // async stage: each wave covers rows w*32 .. w*32+31 of both tiles (4 iters x 8 rows).
    // Per-lane GLOBAL addr carries the inverse swizzle; LDS dest is linear (lane*16).
    {
        const int lrow = l >> 3;                     // row within 8-row chunk; == row&7
        const int scol = ((l & 7) ^ lrow) << 4;      // inverse-swizzled 16-B column
        const unsigned char* gx = X + (size_t)(row0 + w * 32 + lrow) * FDIM + scol;
        const unsigned char* gw = W8 + (size_t)(w * 32 + lrow) * FDIM + scol;
#pragma unroll
        for (int i = 0; i < 4; i++) {
            gload16(gx + (size_t)i * 8 * FDIM, &As[(w * 32 + i * 8) * FDIM]);
            gload16(gw + (size_t)i * 8 * FDIM, &Ws[(w * 32 + i * 8) * FDIM]);
        }
    }
    __syncthreads();   // drains vmcnt (incl. global_load_lds) before LDS reads

    const int m = l & 15, q = l >> 4;
    const int r0 = w * 32;
    const int xa = (m & 7) << 4;    // read-side swizzle (row&7 == m&7 for all fragment rows)

    i64 a0[4], a1[4];
#pragma unroll
    for (int ks = 0; ks < 4; ks++) {
        a0[ks] = *(const i64*)&As[(r0 + m) * FDIM + ((ks * 32 + q * 8) ^ xa)];
        a1[ks] = *(const i64*)&As[(r0 + 16 + m) * FDIM + ((ks * 32 + q * 8) ^ xa)];
    }

    f32x4 acc0[8], acc1[8];
#pragma unroll
    for (int ct = 0; ct < 8; ct++) { acc0[ct] = {0, 0, 0, 0}; acc1[ct] = {0, 0, 0, 0}; }

#pragma unroll
    for (int ct = 0; ct < 8; ct++) {
#pragma unroll
        for (int ks = 0; ks < 4; ks++) {
            i64 b = *(const i64*)&Ws[(ct * 16 + m) * FDIM + ((ks * 32 + q * 8) ^ xa)];
            acc0[ct] = __builtin_amdgcn_mfma_f32_16x16x32_fp8_fp8(a0[ks], b, acc0[ct], 0, 0, 0);
            acc1[ct] = __builtin_amdgcn_mfma_f32_16x16x32_fp8_fp8(a1[ks], b, acc1[ct], 0, 0, 0);
        }
    }

    float dv0[4], dv1[4];
#pragma unroll
    for (int r = 0; r < 4; r++) {
        int row = row0 + r0 + q * 4 + r;
        dv0[r] = (row < N) ? dinv[row] : 0.f;
        dv1[r] = (row + 16 < N) ? dinv[row + 16] : 0.f;
    }

    __syncthreads();
    char* Ab = (char*)&As[0];
#pragma unroll
    for (int ct = 0; ct < 8; ct++) {
#pragma unroll
        for (int r = 0; r < 4; r++) {
            int rl = r0 + q * 4 + r;
            Ab[rl * 128 + ct * 16 + m] = (char)f2fp8(acc0[ct][r] * dv0[r]);
            Ab[(rl + 16) * 128 + ct * 16 + m] = (char)f2fp8(acc1[ct][r] * dv1[r]);
        }
    }
    __syncthreads();
    const uint4* As4 = (const uint4*)Ab;
#pragma unroll
    for (int i = 0; i < 4; i++) {
        int c = t + i * 256;
        int row = c >> 3;
        int col = (c & 7) * 16;
        int grow = row0 + row;
        if (grow < N) *(uint4*)&C[(size_t)grow * FDIM + col] = As4[c];
    }
}

// ---------------- fused pull-aggregate, one node per wave64, fp8 in / fp8 out ----------------
// R11 inner loop (proven): 4 row-groups x 16 lanes, 512-B gathers, 2-deep prefetch,
// 32-bit saddr-form gathers.

__launch_bounds__(256)
__global__ void k_aggregate(const unsigned char* __restrict__ xs8,
                            const int2* __restrict__ rowinfo,
                            const int* __restrict__ csr_src, const float* __restrict__ dinv,
                            const float* __restrict__ bias, unsigned char* __restrict__ out,
                            int N, int do_relu) {
    const int n = (blockIdx.x << 2) + (threadIdx.x >> 6);
    if (n >= N) return;
    const int l = threadIdx.x & 63;
    const int fl = l & 15;      // feature slot: features fl*8 .. fl*8+7
    const int grp = l >> 4;     // row group 0..3
    const unsigned foff = (unsigned)fl << 3;   // byte offset within a 128-B row

    f32x2 acc[4] = {{0, 0}, {0, 0}, {0, 0}, {0, 0}};
    if (grp == 0) {
        uint2 sv = *(const uint2*)(xs8 + (((unsigned)n << 7) | foff));
        fp8x8_add(sv, acc);
    }

    const int2 ri = rowinfo[n];
    const int beg = ri.x;
    const int deg = ri.y;

    for (int base = 0; base < deg; base += 64) {
        const int m = min(64, deg - base);
        int idx = 0;
        if (l < m) idx = csr_src[(unsigned)(beg + base + l)];  // coalesced
        int j = grp;
        if (j < m) {
            int s0 = __shfl(idx, j, 64);
            uint2 v0 = *(const uint2*)(xs8 + (((unsigned)s0 << 7) | foff));
            int j2 = j + 4;
            if (j2 < m) {
                int s1 = __shfl(idx, j2, 64);
                uint2 v1 = *(const uint2*)(xs8 + (((unsigned)s1 << 7) | foff));
                for (j = j2 + 4; j < m; j += 4) {
                    int s2 = __shfl(idx, j, 64);
                    uint2 v2 = *(const uint2*)(xs8 + (((unsigned)s2 << 7) | foff));
                    fp8x8_add(v0, acc);
                    v0 = v1; v1 = v2;
                }
                fp8x8_add(v0, acc);
                fp8x8_add(v1, acc);
            } else {
                fp8x8_add(v0, acc);
            }
        }
    }

    float a[8] = {acc[0][0], acc[0][1], acc[1][0], acc[1][1],
                  acc[2][0], acc[2][1], acc[3][0], acc[3][1]};
#pragma unroll
    for (int k = 0; k < 8; k++) {
        a[k] += __shfl_xor(a[k], 16, 64);
        a[k] += __shfl_xor(a[k], 32, 64);
    }

    if (grp == 0) {
        const float d = dinv[n];
        const float4 b0 = ((const float4*)bias)[fl * 2];
        const float4 b1 = ((const float4*)bias)[fl * 2 + 1];
        const float bb[8] = {b0.x, b0.y, b0.z, b0.w, b1.x, b1.y, b1.z, b1.w};
        float v[8];
#pragma unroll
        for (int k = 0; k < 8; k++) {
            v[k] = d * a[k] + bb[k];
            if (do_relu) v[k] = fmaxf(v[k], 0.f);
        }
        uint2 o;
        unsigned d0 = __builtin_amdgcn_cvt_pk_fp8_f32(v[0], v[1], 0u, false);
        o.x = __builtin_amdgcn_cvt_pk_fp8_f32(v[2], v[3], d0, true);
        unsigned d1 = __builtin_amdgcn_cvt_pk_fp8_f32(v[4], v[5], 0u, false);
        o.y = __builtin_amdgcn_cvt_pk_fp8_f32(v[6], v[7], d1, true);
        ((uint2*)out)[(size_t)n * 16 + fl] = o;
    }
}

// ---------------- pool (fp8 input): 8 lane-groups x 32-node serial runs ----------------

__launch_bounds__(256)
__global__ void k_pool(const unsigned char* __restrict__ x3, const int* __restrict__ batch,
                       float* __restrict__ sums, int N) {
    const int t = threadIdx.x;
    const int fq = t & 31;              // feature quad: features 4*fq .. 4*fq+3
    const int sub = t >> 5;             // node lane 0..7
    const int n0 = blockIdx.x * 256 + sub * 32;
    if (n0 >= N) return;
    const int n1 = (n0 + 32 < N) ? n0 + 32 : N;

    f32x4 acc = {0.f, 0.f, 0.f, 0.f};
    int cur = batch[n0];
    for (int n = n0; n < n1; n++) {
        int g = batch[n];
        if (g != cur) {
            float* s = &sums[cur * FDIM + (fq << 2)];
            atomicAdd(s + 0, acc[0]); atomicAdd(s + 1, acc[1]);
            atomicAdd(s + 2, acc[2]); atomicAdd(s + 3, acc[3]);
            acc = (f32x4){0.f, 0.f, 0.f, 0.f};
            cur = g;
        }
        unsigned w = *(const unsigned*)(x3 + ((size_t)n << 7) + (fq << 2));
        f32x2 lo = __builtin_amdgcn_cvt_pk_f32_fp8(w, false);
        f32x2 hi = __builtin_amdgcn_cvt_pk_f32_fp8(w, true);
        acc[0] += lo[0]; acc[1] += lo[1]; acc[2] += hi[0]; acc[3] += hi[1];
    }
    float* s = &sums[cur * FDIM + (fq << 2)];
    atomicAdd(s + 0, acc[0]); atomicAdd(s + 1, acc[1]);
    atomicAdd(s + 2, acc[2]); atomicAdd(s + 3, acc[3]);
}

// ---------------- per-graph mean + MLP + LayerNorm ----------------

__launch_bounds__(128)
__global__ void k_final(const float* __restrict__ sums, const int* __restrict__ batch, int N,
                        const float* __restrict__ Wm1, const float* __restrict__ bm1,
                        const float* __restrict__ Wm2, const float* __restrict__ bm2,
                        const float* __restrict__ ln_g, const float* __restrict__ ln_b,
                        float* __restrict__ out) {
    const int g = blockIdx.x;
    const int t = threadIdx.x;

    int lo = 0, hi = N;
    while (lo < hi) { int mid = (lo + hi) >> 1; if (batch[mid] < g) lo = mid + 1; else hi = mid; }
    int lo2 = lo, hi2 = N;
    while (lo2 < hi2) { int mid = (lo2 + hi2) >> 1; if (batch[mid] < g + 1) lo2 = mid + 1; else hi2 = mid; }
    float cnt = (float)(lo2 - lo);

    float gl = sums[g * FDIM + t] / fmaxf(cnt, 1.0f);

    __shared__ float gbuf[FDIM];
    __shared__ float hbuf[FDIM];
    __shared__ float wsum[4];
    gbuf[t] = gl;
    __syncthreads();

    float h = bm1[t];
#pragma unroll 8
    for (int k = 0; k < FDIM; k++) h += gbuf[k] * Wm1[k * FDIM + t];
    h = fmaxf(h, 0.f);
    hbuf[t] = h;
    __syncthreads();

    float y = bm2[t];
#pragma unroll 8
    for (int k = 0; k < FDIM; k++) y += hbuf[k] * Wm2[k * FDIM + t];

    float s = y, s2 = y * y;
#pragma unroll
    for (int off = 32; off > 0; off >>= 1) {
        s += __shfl_down(s, off, 64);
        s2 += __shfl_down(s2, off, 64);
    }
    if ((t & 63) == 0) { wsum[t >> 6] = s; wsum[2 + (t >> 6)] = s2; }
    __syncthreads();
    float sum = wsum[0] + wsum[1];
    float sumsq = wsum[2] + wsum[3];
    float mu = sum * (1.0f / FDIM);
    float var = sumsq * (1.0f / FDIM) - mu * mu;
    float r = rsqrtf(var + LN_EPS);
    out[g * FDIM + t] = (y - mu) * r * ln_g[t] + ln_b[t];
}

// ---------------- launch ----------------

extern "C" void kernel_launch(void* const* d_in, const int* in_sizes, int n_in,
                              void* d_out, int out_size, void* d_ws, size_t ws_size,
                              hipStream_t stream) {
    const float* x_in  = (const float*)d_in[0];
    const int*   eidx  = (const int*)d_in[1];
    const int*   batch = (const int*)d_in[2];
    const float* W1 = (const float*)d_in[3];
    const float* b1 = (const float*)d_in[4];
    const float* W2 = (const float*)d_in[5];
    const float* b2 = (const float*)d_in[6];
    const float* W3 = (const float*)d_in[7];
    const float* b3 = (const float*)d_in[8];
    const float* Wm1 = (const float*)d_in[9];
    const float* bm1 = (const float*)d_in[10];
    const float* Wm2 = (const float*)d_in[11];
    const float* bm2 = (const float*)d_in[12];
    const float* ln_g = (const float*)d_in[13];
    const float* ln_b = (const float*)d_in[14];
    float* out = (float*)d_out;

    const int N = in_sizes[0] / FDIM;   // 100000
    const int E = in_sizes[1] / 2;      // 1600000
    const int G = out_size / FDIM;      // 64

    const int* src = eidx;
    const int* dst = eidx + E;

    const int nbkt = (N + BKT_NODES - 1) >> NBKT_SHIFT;        // 391

    // workspace layout
    char* p = (char*)d_ws;
    unsigned* bktA = (unsigned*)p;    p += (size_t)nbkt * BKT_CAP * 4;   // 12.8 MB (packed)
    unsigned char* B0q = (unsigned char*)p; p += (size_t)N * FDIM;       // 12.8 MB (fp8 xs)
    unsigned char* B1q = (unsigned char*)p; p += (size_t)N * FDIM;       // 12.8 MB (fp8 agg)
    int* csr_src = (int*)p;           p += (size_t)nbkt * BKT_CAP * 4;   // 12.8 MB
    int2* rowinfo = (int2*)p;         p += (size_t)N * 8;
    float* dinv = (float*)p;          p += (size_t)N * 4;
    ushort* Wt_b = (ushort*)p;        p += 16384 * 2;
    unsigned char* Wt8 = (unsigned char*)p; p += 2 * 16384;
    float* gsums = (float*)p;         p += (size_t)G * FDIM * 4;
    int* bcur = (int*)p;              p += MAXBKT * 4;

    const int TPB = 256;
    dim3 blk(TPB);
    dim3 gAgg((N + 3) / 4);
    dim3 gTile((N + 127) / 128);
    const int nEb = (E + 4095) / 4096;

    // ---- prep (also zeroes gsums/bcur) + build ----
    k_prep_w<<<dim3(192), blk, 0, stream>>>(W1, W2, W3, Wt_b, Wt8, gsums, bcur);
    k_bkt_scatter<<<dim3(nEb), blk, 0, stream>>>(src, dst, bcur, bktA, E, nbkt);
    k_build<<<dim3(nbkt), dim3(512), 0, stream>>>(bktA, bcur, rowinfo, dinv, csr_src, N);

    // ---- layer 1 (fp32 input, bf16 MFMA) ----
    k_gemm_f32<<<gTile, blk, 0, stream>>>(x_in, Wt_b, dinv, B0q, N);
    k_aggregate<<<gAgg, blk, 0, stream>>>(B0q, rowinfo, csr_src, dinv, b1, B1q, N, 1);

    // ---- layer 2 (fp8 MFMA) ----
    k_gemm_fp8<<<gTile, blk, 0, stream>>>(B1q, Wt8, dinv, B0q, N);
    k_aggregate<<<gAgg, blk, 0, stream>>>(B0q, rowinfo, csr_src, dinv, b2, B1q, N, 1);

    // ---- layer 3 (fp8 MFMA, no relu) ----
    k_gemm_fp8<<<gTile, blk, 0, stream>>>(B1q, Wt8 + 16384, dinv, B0q, N);
    k_aggregate<<<gAgg, blk, 0, stream>>>(B0q, rowinfo, csr_src, dinv, b3, B1q, N, 0);

    // ---- pool + MLP + LN ----
    k_pool<<<dim3((N + 255) / 256), blk, 0, stream>>>(B1q, batch, gsums, N);
    k_final<<<dim3(G), dim3(FDIM), 0, stream>>>(gsums, batch, N, Wm1, bm1, Wm2, bm2,
                                                ln_g, ln_b, out);
}

// Round 5
// 378.007 us; speedup vs baseline: 1.2042x; 1.0276x over previous
//
#include <hip/hip_runtime.h>

#define FDIM 128
#define LN_EPS 1e-5f
#define NBKT_SHIFT 8           // 256 nodes per bucket
#define BKT_NODES 256
#define MAXBKT 512             // supports N <= 131072
#define CAP_SHIFT 13           // 8192 edge capacity per bucket (mean 4096+pad, ~40 sigma)
#define BKT_CAP 8192

typedef short bf16x8 __attribute__((ext_vector_type(8)));
typedef float f32x4 __attribute__((ext_vector_type(4)));
typedef float f32x2 __attribute__((ext_vector_type(2)));
typedef ushort u16x8 __attribute__((ext_vector_type(8)));
typedef unsigned long long u64;
typedef long long i64;

static __device__ __forceinline__ ushort f2bf(float f) {
    union { float f; unsigned u; } v; v.f = f;
    unsigned r = v.u + 0x7FFFu + ((v.u >> 16) & 1u);  // RNE
    return (ushort)(r >> 16);
}
// packed f32x2 -> bf16x2 (RNE), single HW instruction
static __device__ __forceinline__ unsigned cvt_pk_bf16(float lo, float hi) {
    unsigned r;
    asm("v_cvt_pk_bf16_f32 %0, %1, %2" : "=v"(r) : "v"(lo), "v"(hi));
    return r;
}
// fp8 e4m3 (OCP on gfx950) encode/decode via HW converts
static __device__ __forceinline__ unsigned char f2fp8(float f) {
    return (unsigned char)__builtin_amdgcn_cvt_pk_fp8_f32(f, f, 0u, false);
}
static __device__ __forceinline__ float fp8tof(unsigned char b) {
    f32x2 p = __builtin_amdgcn_cvt_pk_f32_fp8((unsigned)b, false);
    return p[0];
}
static __device__ __forceinline__ void fp8x8_add(uint2 w, f32x2* acc) {
    acc[0] += __builtin_amdgcn_cvt_pk_f32_fp8(w.x, false);
    acc[1] += __builtin_amdgcn_cvt_pk_f32_fp8(w.x, true);
    acc[2] += __builtin_amdgcn_cvt_pk_f32_fp8(w.y, false);
    acc[3] += __builtin_amdgcn_cvt_pk_f32_fp8(w.y, true);
}

// async global->LDS, 16 B per lane (wave-uniform LDS base + lane*16)
typedef __attribute__((address_space(3))) unsigned char lds_uchar;
typedef const __attribute__((address_space(1))) unsigned char glob_uchar;
static __device__ __forceinline__ void gload16(const unsigned char* g, unsigned char* l) {
    __builtin_amdgcn_global_load_lds((glob_uchar*)g, (lds_uchar*)l, 16, 0, 0);
}

// ---------------- bucketed edge scatter (fixed-capacity buckets) ----------------
// 4096 edges/block. Packs (src,local_dst) into one u32: src<<8 | (dst & 255).

__launch_bounds__(256)
__global__ void k_bkt_scatter(const int* __restrict__ src, const int* __restrict__ dst,
                              int* __restrict__ bcur, unsigned* __restrict__ bktA,
                              int E, int nbkt) {
    __shared__ int h[2][MAXBKT], lbase[2][MAXBKT], lcur[2][MAXBKT];
    const int t = threadIdx.x;
    const int half = t >> 7;
    for (int i = t; i < 2 * MAXBKT; i += 256) ((int*)h)[i] = 0;
    __syncthreads();
    const int E4 = E >> 2;   // E multiple of 4
    const int4* s4p = (const int4*)src;
    const int4* d4p = (const int4*)dst;
    int4 sv[4], dv[4]; bool ok[4];
#pragma unroll
    for (int r = 0; r < 4; r++) {
        int i4 = blockIdx.x * 1024 + r * 256 + t;
        ok[r] = (i4 < E4);
        if (ok[r]) {
            sv[r] = s4p[i4]; dv[r] = d4p[i4];
            atomicAdd(&h[half][dv[r].x >> NBKT_SHIFT], 1);
            atomicAdd(&h[half][dv[r].y >> NBKT_SHIFT], 1);
            atomicAdd(&h[half][dv[r].z >> NBKT_SHIFT], 1);
            atomicAdd(&h[half][dv[r].w >> NBKT_SHIFT], 1);
        }
    }
    __syncthreads();
    for (int i = t; i < 2 * nbkt; i += 256) {
        const int hh = (i >= nbkt) ? 1 : 0;
        const int b = hh ? (i - nbkt) : i;
        const int c = h[hh][b];
        lbase[hh][b] = c ? ((b << CAP_SHIFT) + atomicAdd(&bcur[b], c)) : 0;
        lcur[hh][b] = 0;
    }
    __syncthreads();
#pragma unroll
    for (int r = 0; r < 4; r++) {
        if (!ok[r]) continue;
        int ss[4] = {sv[r].x, sv[r].y, sv[r].z, sv[r].w};
        int dd[4] = {dv[r].x, dv[r].y, dv[r].z, dv[r].w};
#pragma unroll
        for (int j = 0; j < 4; j++) {
            int b = dd[j] >> NBKT_SHIFT;
            int p = atomicAdd(&lcur[half][b], 1);
            bktA[(size_t)lbase[half][b] + p] =
                ((unsigned)ss[j] << NBKT_SHIFT) | (unsigned)(dd[j] & (BKT_NODES - 1));
        }
    }
}

// merged per-bucket: degree count -> wave scan (PADDED to mult of 8) -> rowinfo/dinv ->
// LDS-sorted CSR fill; padding slots point at the zero row (index N).

__launch_bounds__(512)
__global__ void k_build(const unsigned* __restrict__ bktA, const int* __restrict__ bcur,
                        int2* __restrict__ rowinfo, float* __restrict__ dinv,
                        int* __restrict__ csr_src, int N) {
    __shared__ int sorted[BKT_CAP];      // 32 KB
    __shared__ int cnt[BKT_NODES];
    __shared__ int cur[BKT_NODES];
    __shared__ int wpart[4], wbase[4];
    __shared__ int stot;
    const int t = threadIdx.x;
    const int b = blockIdx.x;
    const int nb = b << NBKT_SHIFT;
    if (t < BKT_NODES) cnt[t] = 0;
    __syncthreads();
    const int beg = b << CAP_SHIFT;
    const int tot = bcur[b];
    // pass 1: histogram (coalesced global read)
    for (int i = t; i < tot; i += 512)
        atomicAdd(&cnt[bktA[beg + i] & (BKT_NODES - 1)], 1);
    __syncthreads();
    // scan over 256 padded counters (4 waves)
    const int lane = t & 63, wv = t >> 6;
    int my = 0, pm = 0, x = 0;
    if (t < BKT_NODES) {
        my = cnt[t];
        pm = (my + 7) & ~7;        // pad each row to multiple of 8
        x = pm;
#pragma unroll
        for (int off = 1; off < 64; off <<= 1) {
            int y = __shfl_up(x, off, 64);
            if (lane >= off) x += y;
        }
        if (lane == 63) wpart[wv] = x;
    }
    __syncthreads();
    if (t == 0) {
        int s = 0;
        for (int w = 0; w < 4; w++) { int tmp = wpart[w]; wbase[w] = s; s += tmp; }
    }
    __syncthreads();
    if (t < BKT_NODES) {
        const int incl = x + wbase[wv];
        const int rbeg = incl - pm;          // local exclusive prefix (padded layout)
        cur[t] = rbeg;
        const int n = nb + t;
        if (n < N) {
            rowinfo[n] = make_int2(beg + rbeg, pm);
            dinv[n] = rsqrtf((float)(my + 1));  // +1 self-loop (TRUE degree)
        }
        for (int i = rbeg + my; i < rbeg + pm; i++) sorted[i] = N;  // zero-row pads
        if (t == BKT_NODES - 1) stot = incl;
    }
    __syncthreads();
    // pass 2: scatter into LDS (global re-read is L2-hot), then coalesced dump
    for (int i = t; i < tot; i += 512) {
        unsigned pr = bktA[beg + i];
        int d = pr & (BKT_NODES - 1);
        int p = atomicAdd(&cur[d], 1);
        sorted[p] = (int)(pr >> NBKT_SHIFT);
    }
    __syncthreads();
    const int tp = stot;
    for (int i = t; i < tp; i += 512)
        csr_src[beg + i] = sorted[i];
}

// ---------------- W prep: layer0 -> bf16 Wt_b[n][k]; layers 1,2 -> fp8 Wt8 ----------------
// Also zeroes gsums, bcur, and the zero-row (index N) of both fp8 node buffers.

__global__ void k_prep_w(const float* __restrict__ Wa, const float* __restrict__ Wb,
                         const float* __restrict__ Wc, ushort* __restrict__ Wt_b,
                         unsigned char* __restrict__ Wt8, float* __restrict__ gsums,
                         int* __restrict__ bcur, unsigned char* __restrict__ B0q,
                         unsigned char* __restrict__ B1q, int N) {
    int idx = blockIdx.x * 256 + threadIdx.x;  // 192*256 = 49152 = 3*16384
    int layer = idx >> 14;
    int r = idx & 16383;
    int nn = r >> 7, kk = r & 127;
    if (layer == 0) {
        Wt_b[r] = f2bf(Wa[kk * 128 + nn]);
    } else {
        const float* W = (layer == 1) ? Wb : Wc;
        Wt8[(size_t)(layer - 1) * 16384 + r] = f2fp8(W[kk * 128 + nn]);
    }
    if (idx < 8192) gsums[idx] = 0.f;
    if (idx < MAXBKT) bcur[idx] = 0;
    uint4 z = {0, 0, 0, 0};
    if (idx < 8) ((uint4*)(B0q + (size_t)N * FDIM))[idx] = z;
    else if (idx < 16) ((uint4*)(B1q + (size_t)N * FDIM))[idx - 8] = z;
}

// ---------------- layer-1 MFMA GEMM (bf16): xs(fp8) = dinv .* (X_f32 @ W) ----------------

__launch_bounds__(256)
__global__ void k_gemm_f32(const float* __restrict__ X, const ushort* __restrict__ Wt,
                           const float* __restrict__ dinv, unsigned char* __restrict__ C,
                           int N) {
    __shared__ __align__(16) ushort As[128][136];
    __shared__ ushort Ws[128][136];
    const int t = threadIdx.x;
    const int row0 = blockIdx.x * 128;

#pragma unroll
    for (int i = 0; i < 8; i++) {
        int c = t + i * 256;
        int r = c >> 4, c8 = (c & 15) * 8;
        *(bf16x8*)&Ws[r][c8] = *(const bf16x8*)&Wt[r * 128 + c8];
    }
#pragma unroll
    for (int i = 0; i < 8; i++) {
        int c = t + i * 256;
        int r = c >> 4, c8 = (c & 15) * 8;
        int row = row0 + r;
        bf16x8 pk = {0, 0, 0, 0, 0, 0, 0, 0};
        if (row < N) {
            const float* sp = X + (size_t)row * FDIM + c8;
            float4 u0 = *(const float4*)(sp);
            float4 u1 = *(const float4*)(sp + 4);
            union { unsigned u[4]; bf16x8 v; } cv;
            cv.u[0] = cvt_pk_bf16(u0.x, u0.y);
            cv.u[1] = cvt_pk_bf16(u0.z, u0.w);
            cv.u[2] = cvt_pk_bf16(u1.x, u1.y);
            cv.u[3] = cvt_pk_bf16(u1.z, u1.w);
            pk = cv.v;
        }
        *(bf16x8*)&As[r][c8] = pk;
    }
    __syncthreads();

    const int w = t >> 6, l = t & 63;
    const int m = l & 15, q = l >> 4;
    const int r0 = w * 32;

    bf16x8 a0[4], a1[4];
#pragma unroll
    for (int ks = 0; ks < 4; ks++) {
        a0[ks] = *(const bf16x8*)&As[r0 + m][ks * 32 + q * 8];
        a1[ks] = *(const bf16x8*)&As[r0 + 16 + m][ks * 32 + q * 8];
    }

    f32x4 acc0[8], acc1[8];
#pragma unroll
    for (int ct = 0; ct < 8; ct++) { acc0[ct] = {0, 0, 0, 0}; acc1[ct] = {0, 0, 0, 0}; }

#pragma unroll
    for (int ct = 0; ct < 8; ct++) {
#pragma unroll
        for (int ks = 0; ks < 4; ks++) {
            bf16x8 b = *(const bf16x8*)&Ws[ct * 16 + m][ks * 32 + q * 8];
            acc0[ct] = __builtin_amdgcn_mfma_f32_16x16x32_bf16(a0[ks], b, acc0[ct], 0, 0, 0);
            acc1[ct] = __builtin_amdgcn_mfma_f32_16x16x32_bf16(a1[ks], b, acc1[ct], 0, 0, 0);
        }
    }

    float dv0[4], dv1[4];
#pragma unroll
    for (int r = 0; r < 4; r++) {
        int row = row0 + r0 + q * 4 + r;
        dv0[r] = (row < N) ? dinv[row] : 0.f;
        dv1[r] = (row + 16 < N) ? dinv[row + 16] : 0.f;
    }

    // stage fp8 tile into LDS (reuse As), then coalesced 16-B stores
    __syncthreads();
    char* Ab = (char*)&As[0][0];
#pragma unroll
    for (int ct = 0; ct < 8; ct++) {
#pragma unroll
        for (int r = 0; r < 4; r++) {
            int rl = r0 + q * 4 + r;
            Ab[rl * 128 + ct * 16 + m] = (char)f2fp8(acc0[ct][r] * dv0[r]);
            Ab[(rl + 16) * 128 + ct * 16 + m] = (char)f2fp8(acc1[ct][r] * dv1[r]);
        }
    }
    __syncthreads();
    const uint4* As4 = (const uint4*)Ab;
#pragma unroll
    for (int i = 0; i < 4; i++) {
        int c = t + i * 256;
        int row = c >> 3;
        int col = (c & 7) * 16;
        int grow = row0 + row;
        if (grow < N) *(uint4*)&C[(size_t)grow * FDIM + col] = As4[c];
    }
}

// ---------------- layers 2/3 MFMA GEMM (fp8 x fp8): xs(fp8) = dinv .* (A_fp8 @ W_fp8) ----
// A/W tiles staged via async global_load_lds (16 B/lane) with both-sides XOR swizzle:
// global source column pre-swizzled (col = 16*((l&7)^(l>>3))), LDS linear, reads XOR
// ((row&7)<<4). Read bank = (ks*8+q*2)^((m&7)<<2): 4 lanes/bank (parity with +16 pad).

__launch_bounds__(256)
__global__ void k_gemm_fp8(const unsigned char* __restrict__ X,
                           const unsigned char* __restrict__ W8,
                           const float* __restrict__ dinv, unsigned char* __restrict__ C,
                           int N) {
    __shared__ __align__(16) unsigned char As[128 * 128];
    __shared__ __align__(16) unsigned char Ws[128 * 128];
    const int t = threadIdx.x;
    const int w = t >> 6, l = t & 63;
    const int row0 = blockIdx.x * 128;

    // async stage: each wave covers rows w*32 .. w*32+31 of both tiles (4 iters x 8 rows).
    // Per-lane GLOBAL addr carries the inverse swizzle; LDS dest is linear (lane*16).
    {
        const int lrow = l >> 3;                     // row within 8-row chunk; == row&7
        const int scol = ((l & 7) ^ lrow) << 4;      // inverse-swizzled 16-B column
        const unsigned char* gx = X + (size_t)(row0 + w * 32 + lrow) * FDIM + scol;
        const unsigned char* gw = W8 + (size_t)(w * 32 + lrow) * FDIM + scol;
#pragma unroll
        for (int i = 0; i < 4; i++) {
            gload16(gx + (size_t)i * 8 * FDIM, &As[(w * 32 + i * 8) * FDIM]);
            gload16(gw + (size_t)i * 8 * FDIM, &Ws[(w * 32 + i * 8) * FDIM]);
        }
    }
    __syncthreads();   // drains vmcnt (incl. global_load_lds) before LDS reads

    const int m = l & 15, q = l >> 4;
    const int r0 = w * 32;
    const int xa = (m & 7) << 4;    // read-side swizzle (row&7 == m&7 for all fragment rows)

    i64 a0[4], a1[4];
#pragma unroll
    for (int ks = 0; ks < 4; ks++) {
        a0[ks] = *(const i64*)&As[(r0 + m) * FDIM + ((ks * 32 + q * 8) ^ xa)];
        a1[ks] = *(const i64*)&As[(r0 + 16 + m) * FDIM + ((ks * 32 + q * 8) ^ xa)];
    }

    f32x4 acc0[8], acc1[8];
#pragma unroll
    for (int ct = 0; ct < 8; ct++) { acc0[ct] = {0, 0, 0, 0}; acc1[ct] = {0, 0, 0, 0}; }

#pragma unroll
    for (int ct = 0; ct < 8; ct++) {
#pragma unroll
        for (int ks = 0; ks < 4; ks++) {
            i64 b = *(const i64*)&Ws[(ct * 16 + m) * FDIM + ((ks * 32 + q * 8) ^ xa)];
            acc0[ct] = __builtin_amdgcn_mfma_f32_16x16x32_fp8_fp8(a0[ks], b, acc0[ct], 0, 0, 0);
            acc1[ct] = __builtin_amdgcn_mfma_f32_16x16x32_fp8_fp8(a1[ks], b, acc1[ct], 0, 0, 0);
        }
    }

    float dv0[4], dv1[4];
#pragma unroll
    for (int r = 0; r < 4; r++) {
        int row = row0 + r0 + q * 4 + r;
        dv0[r] = (row < N) ? dinv[row] : 0.f;
        dv1[r] = (row + 16 < N) ? dinv[row + 16] : 0.f;
    }

    __syncthreads();
    char* Ab = (char*)&As[0];
#pragma unroll
    for (int ct = 0; ct < 8; ct++) {
#pragma unroll
        for (int r = 0; r < 4; r++) {
            int rl = r0 + q * 4 + r;
            Ab[rl * 128 + ct * 16 + m] = (char)f2fp8(acc0[ct][r] * dv0[r]);
            Ab[(rl + 16) * 128 + ct * 16 + m] = (char)f2fp8(acc1[ct][r] * dv1[r]);
        }
    }
    __syncthreads();
    const uint4* As4 = (const uint4*)Ab;
#pragma unroll
    for (int i = 0; i < 4; i++) {
        int c = t + i * 256;
        int row = c >> 3;
        int col = (c & 7) * 16;
        int grow = row0 + row;
        if (grow < N) *(uint4*)&C[(size_t)grow * FDIM + col] = As4[c];
    }
}

// ---------------- fused pull-aggregate, one node per wave64, fp8 in / fp8 out ----------------
// Degrees padded to multiple of 8 (pad slots -> zero row N): branch-free 4-deep pipeline,
// 4 row-groups x 16 lanes, 512-B gathers, 32-bit saddr-form addressing.

__launch_bounds__(512)
__global__ void k_aggregate(const unsigned char* __restrict__ xs8,
                            const int2* __restrict__ rowinfo,
                            const int* __restrict__ csr_src, const float* __restrict__ dinv,
                            const float* __restrict__ bias, unsigned char* __restrict__ out,
                            int N, int do_relu) {
    const int n = (blockIdx.x << 3) + (threadIdx.x >> 6);
    if (n >= N) return;
    const int l = threadIdx.x & 63;
    const int fl = l & 15;      // feature slot: features fl*8 .. fl*8+7
    const int grp = l >> 4;     // row group 0..3
    const unsigned foff = (unsigned)fl << 3;   // byte offset within a 128-B row

    f32x2 acc[4] = {{0, 0}, {0, 0}, {0, 0}, {0, 0}};
    if (grp == 0) {
        uint2 sv = *(const uint2*)(xs8 + (((unsigned)n << 7) | foff));
        fp8x8_add(sv, acc);
    }

    const int2 ri = rowinfo[n];
    const int beg = ri.x;
    const int deg = ri.y;       // padded: multiple of 8 (0 if isolated)

    for (int base = 0; base < deg; base += 64) {
        const int m = min(64, deg - base);   // multiple of 8
        int idx = 0;
        if (l < m) idx = csr_src[(unsigned)(beg + base + l)];  // coalesced
        // group grp owns j = grp, grp+4, ..., m-4+grp  (count m/4, even)
        int s0 = __shfl(idx, grp, 64);
        uint2 v0 = *(const uint2*)(xs8 + (((unsigned)s0 << 7) | foff));
        int s1 = __shfl(idx, grp + 4, 64);
        uint2 v1 = *(const uint2*)(xs8 + (((unsigned)s1 << 7) | foff));
        if (m >= 16) {
            int s2 = __shfl(idx, grp + 8, 64);
            uint2 v2 = *(const uint2*)(xs8 + (((unsigned)s2 << 7) | foff));
            int s3 = __shfl(idx, grp + 12, 64);
            uint2 v3 = *(const uint2*)(xs8 + (((unsigned)s3 << 7) | foff));
            for (int j = grp + 16; j + 8 <= m + grp; j += 8) {
                int sa = __shfl(idx, j, 64);
                int sb = __shfl(idx, j + 4, 64);
                fp8x8_add(v0, acc);
                uint2 va = *(const uint2*)(xs8 + (((unsigned)sa << 7) | foff));
                fp8x8_add(v1, acc);
                uint2 vb = *(const uint2*)(xs8 + (((unsigned)sb << 7) | foff));
                v0 = v2; v1 = v3; v2 = va; v3 = vb;
            }
            fp8x8_add(v0, acc); fp8x8_add(v1, acc);
            fp8x8_add(v2, acc); fp8x8_add(v3, acc);
        } else {
            fp8x8_add(v0, acc); fp8x8_add(v1, acc);
        }
    }

    float a[8] = {acc[0][0], acc[0][1], acc[1][0], acc[1][1],
                  acc[2][0], acc[2][1], acc[3][0], acc[3][1]};
#pragma unroll
    for (int k = 0; k < 8; k++) {
        a[k] += __shfl_xor(a[k], 16, 64);
        a[k] += __shfl_xor(a[k], 32, 64);
    }

    if (grp == 0) {
        const float d = dinv[n];
        const float4 b0 = ((const float4*)bias)[fl * 2];
        const float4 b1 = ((const float4*)bias)[fl * 2 + 1];
        const float bb[8] = {b0.x, b0.y, b0.z, b0.w, b1.x, b1.y, b1.z, b1.w};
        float v[8];
#pragma unroll
        for (int k = 0; k < 8; k++) {
            v[k] = d * a[k] + bb[k];
            if (do_relu) v[k] = fmaxf(v[k], 0.f);
        }
        uint2 o;
        unsigned d0 = __builtin_amdgcn_cvt_pk_fp8_f32(v[0], v[1], 0u, false);
        o.x = __builtin_amdgcn_cvt_pk_fp8_f32(v[2], v[3], d0, true);
        unsigned d1 = __builtin_amdgcn_cvt_pk_fp8_f32(v[4], v[5], 0u, false);
        o.y = __builtin_amdgcn_cvt_pk_fp8_f32(v[6], v[7], d1, true);
        ((uint2*)out)[(size_t)n * 16 + fl] = o;
    }
}

// ---------------- pool (fp8 input): 8 lane-groups x 32-node serial runs ----------------

__launch_bounds__(256)
__global__ void k_pool(const unsigned char* __restrict__ x3, const int* __restrict__ batch,
                       float* __restrict__ sums, int N) {
    const int t = threadIdx.x;
    const int fq = t & 31;              // feature quad: features 4*fq .. 4*fq+3
    const int sub = t >> 5;             // node lane 0..7
    const int n0 = blockIdx.x * 256 + sub * 32;
    if (n0 >= N) return;
    const int n1 = (n0 + 32 < N) ? n0 + 32 : N;

    f32x4 acc = {0.f, 0.f, 0.f, 0.f};
    int cur = batch[n0];
    for (int n = n0; n < n1; n++) {
        int g = batch[n];
        if (g != cur) {
            float* s = &sums[cur * FDIM + (fq << 2)];
            atomicAdd(s + 0, acc[0]); atomicAdd(s + 1, acc[1]);
            atomicAdd(s + 2, acc[2]); atomicAdd(s + 3, acc[3]);
            acc = (f32x4){0.f, 0.f, 0.f, 0.f};
            cur = g;
        }
        unsigned w = *(const unsigned*)(x3 + ((size_t)n << 7) + (fq << 2));
        f32x2 lo = __builtin_amdgcn_cvt_pk_f32_fp8(w, false);
        f32x2 hi = __builtin_amdgcn_cvt_pk_f32_fp8(w, true);
        acc[0] += lo[0]; acc[1] += lo[1]; acc[2] += hi[0]; acc[3] += hi[1];
    }
    float* s = &sums[cur * FDIM + (fq << 2)];
    atomicAdd(s + 0, acc[0]); atomicAdd(s + 1, acc[1]);
    atomicAdd(s + 2, acc[2]); atomicAdd(s + 3, acc[3]);
}

// ---------------- per-graph mean + MLP + LayerNorm ----------------

__launch_bounds__(128)
__global__ void k_final(const float* __restrict__ sums, const int* __restrict__ batch, int N,
                        const float* __restrict__ Wm1, const float* __restrict__ bm1,
                        const float* __restrict__ Wm2, const float* __restrict__ bm2,
                        const float* __restrict__ ln_g, const float* __restrict__ ln_b,
                        float* __restrict__ out) {
    const int g = blockIdx.x;
    const int t = threadIdx.x;

    int lo = 0, hi = N;
    while (lo < hi) { int mid = (lo + hi) >> 1; if (batch[mid] < g) lo = mid + 1; else hi = mid; }
    int lo2 = lo, hi2 = N;
    while (lo2 < hi2) { int mid = (lo2 + hi2) >> 1; if (batch[mid] < g + 1) lo2 = mid + 1; else hi2 = mid; }
    float cnt = (float)(lo2 - lo);

    float gl = sums[g * FDIM + t] / fmaxf(cnt, 1.0f);

    __shared__ float gbuf[FDIM];
    __shared__ float hbuf[FDIM];
    __shared__ float wsum[4];
    gbuf[t] = gl;
    __syncthreads();

    float h = bm1[t];
#pragma unroll 8
    for (int k = 0; k < FDIM; k++) h += gbuf[k] * Wm1[k * FDIM + t];
    h = fmaxf(h, 0.f);
    hbuf[t] = h;
    __syncthreads();

    float y = bm2[t];
#pragma unroll 8
    for (int k = 0; k < FDIM; k++) y += hbuf[k] * Wm2[k * FDIM + t];

    float s = y, s2 = y * y;
#pragma unroll
    for (int off = 32; off > 0; off >>= 1) {
        s += __shfl_down(s, off, 64);
        s2 += __shfl_down(s2, off, 64);
    }
    if ((t & 63) == 0) { wsum[t >> 6] = s; wsum[2 + (t >> 6)] = s2; }
    __syncthreads();
    float sum = wsum[0] + wsum[1];
    float sumsq = wsum[2] + wsum[3];
    float mu = sum * (1.0f / FDIM);
    float var = sumsq * (1.0f / FDIM) - mu * mu;
    float r = rsqrtf(var + LN_EPS);
    out[g * FDIM + t] = (y - mu) * r * ln_g[t] + ln_b[t];
}

// ---------------- launch ----------------

extern "C" void kernel_launch(void* const* d_in, const int* in_sizes, int n_in,
                              void* d_out, int out_size, void* d_ws, size_t ws_size,
                              hipStream_t stream) {
    const float* x_in  = (const float*)d_in[0];
    const int*   eidx  = (const int*)d_in[1];
    const int*   batch = (const int*)d_in[2];
    const float* W1 = (const float*)d_in[3];
    const float* b1 = (const float*)d_in[4];
    const float* W2 = (const float*)d_in[5];
    const float* b2 = (const float*)d_in[6];
    const float* W3 = (const float*)d_in[7];
    const float* b3 = (const float*)d_in[8];
    const float* Wm1 = (const float*)d_in[9];
    const float* bm1 = (const float*)d_in[10];
    const float* Wm2 = (const float*)d_in[11];
    const float* bm2 = (const float*)d_in[12];
    const float* ln_g = (const float*)d_in[13];
    const float* ln_b = (const float*)d_in[14];
    float* out = (float*)d_out;

    const int N = in_sizes[0] / FDIM;   // 100000
    const int E = in_sizes[1] / 2;      // 1600000
    const int G = out_size / FDIM;      // 64

    const int* src = eidx;
    const int* dst = eidx + E;

    const int nbkt = (N + BKT_NODES - 1) >> NBKT_SHIFT;        // 391

    // workspace layout (B0q/B1q have one extra zero row at index N)
    char* p = (char*)d_ws;
    unsigned* bktA = (unsigned*)p;    p += (size_t)nbkt * BKT_CAP * 4;   // 12.8 MB (packed)
    unsigned char* B0q = (unsigned char*)p; p += (size_t)(N + 1) * FDIM; // 12.8 MB (fp8 xs)
    unsigned char* B1q = (unsigned char*)p; p += (size_t)(N + 1) * FDIM; // 12.8 MB (fp8 agg)
    int* csr_src = (int*)p;           p += (size_t)nbkt * BKT_CAP * 4;   // 12.8 MB
    int2* rowinfo = (int2*)p;         p += (size_t)N * 8;
    float* dinv = (float*)p;          p += (size_t)N * 4;
    ushort* Wt_b = (ushort*)p;        p += 16384 * 2;
    unsigned char* Wt8 = (unsigned char*)p; p += 2 * 16384;
    float* gsums = (float*)p;         p += (size_t)G * FDIM * 4;
    int* bcur = (int*)p;              p += MAXBKT * 4;

    const int TPB = 256;
    dim3 blk(TPB);
    dim3 gAgg((N + 7) / 8);
    dim3 gTile((N + 127) / 128);
    const int nEb = (E + 4095) / 4096;

    // ---- prep (also zeroes gsums/bcur/zero-rows) + build ----
    k_prep_w<<<dim3(192), blk, 0, stream>>>(W1, W2, W3, Wt_b, Wt8, gsums, bcur, B0q, B1q, N);
    k_bkt_scatter<<<dim3(nEb), blk, 0, stream>>>(src, dst, bcur, bktA, E, nbkt);
    k_build<<<dim3(nbkt), dim3(512), 0, stream>>>(bktA, bcur, rowinfo, dinv, csr_src, N);

    // ---- layer 1 (fp32 input, bf16 MFMA) ----
    k_gemm_f32<<<gTile, blk, 0, stream>>>(x_in, Wt_b, dinv, B0q, N);
    k_aggregate<<<gAgg, dim3(512), 0, stream>>>(B0q, rowinfo, csr_src, dinv, b1, B1q, N, 1);

    // ---- layer 2 (fp8 MFMA) ----
    k_gemm_fp8<<<gTile, blk, 0, stream>>>(B1q, Wt8, dinv, B0q, N);
    k_aggregate<<<gAgg, dim3(512), 0, stream>>>(B0q, rowinfo, csr_src, dinv, b2, B1q, N, 1);

    // ---- layer 3 (fp8 MFMA, no relu) ----
    k_gemm_fp8<<<gTile, blk, 0, stream>>>(B1q, Wt8 + 16384, dinv, B0q, N);
    k_aggregate<<<gAgg, dim3(512), 0, stream>>>(B0q, rowinfo, csr_src, dinv, b3, B1q, N, 0);

    // ---- pool + MLP + LN ----
    k_pool<<<dim3((N + 255) / 256), blk, 0, stream>>>(B1q, batch, gsums, N);
    k_final<<<dim3(G), dim3(FDIM), 0, stream>>>(gsums, batch, N, Wm1, bm1, Wm2, bm2,
                                                ln_g, ln_b, out);
}

// Round 6
// 372.796 us; speedup vs baseline: 1.2210x; 1.0140x over previous
//
#include <hip/hip_runtime.h>

#define FDIM 128
#define LN_EPS 1e-5f
#define NBKT_SHIFT 8           // 256 nodes per bucket
#define BKT_NODES 256
#define MAXBKT 512             // supports N <= 131072
#define CAP_SHIFT 13           // 8192 edge capacity per bucket (mean 4096+pad, ~40 sigma)
#define BKT_CAP 8192

typedef short bf16x8 __attribute__((ext_vector_type(8)));
typedef float f32x4 __attribute__((ext_vector_type(4)));
typedef float f32x2 __attribute__((ext_vector_type(2)));
typedef ushort u16x8 __attribute__((ext_vector_type(8)));
typedef unsigned long long u64;
typedef long long i64;

static __device__ __forceinline__ ushort f2bf(float f) {
    union { float f; unsigned u; } v; v.f = f;
    unsigned r = v.u + 0x7FFFu + ((v.u >> 16) & 1u);  // RNE
    return (ushort)(r >> 16);
}
// packed f32x2 -> bf16x2 (RNE), single HW instruction
static __device__ __forceinline__ unsigned cvt_pk_bf16(float lo, float hi) {
    unsigned r;
    asm("v_cvt_pk_bf16_f32 %0, %1, %2" : "=v"(r) : "v"(lo), "v"(hi));
    return r;
}
// fp8 e4m3 (OCP on gfx950) encode/decode via HW converts
static __device__ __forceinline__ unsigned char f2fp8(float f) {
    return (unsigned char)__builtin_amdgcn_cvt_pk_fp8_f32(f, f, 0u, false);
}
static __device__ __forceinline__ float fp8tof(unsigned char b) {
    f32x2 p = __builtin_amdgcn_cvt_pk_f32_fp8((unsigned)b, false);
    return p[0];
}
static __device__ __forceinline__ void fp8x8_add(uint2 w, f32x2* acc) {
    acc[0] += __builtin_amdgcn_cvt_pk_f32_fp8(w.x, false);
    acc[1] += __builtin_amdgcn_cvt_pk_f32_fp8(w.x, true);
    acc[2] += __builtin_amdgcn_cvt_pk_f32_fp8(w.y, false);
    acc[3] += __builtin_amdgcn_cvt_pk_f32_fp8(w.y, true);
}

// async global->LDS, 16 B per lane (wave-uniform LDS base + lane*16)
typedef __attribute__((address_space(3))) unsigned char lds_uchar;
typedef const __attribute__((address_space(1))) unsigned char glob_uchar;
static __device__ __forceinline__ void gload16(const unsigned char* g, unsigned char* l) {
    __builtin_amdgcn_global_load_lds((glob_uchar*)g, (lds_uchar*)l, 16, 0, 0);
}

// ---------------- bucketed edge scatter (fixed-capacity buckets) ----------------
// 4096 edges/block. Packs (src,local_dst) into one u32: src<<8 | (dst & 255).

__launch_bounds__(256)
__global__ void k_bkt_scatter(const int* __restrict__ src, const int* __restrict__ dst,
                              int* __restrict__ bcur, unsigned* __restrict__ bktA,
                              int E, int nbkt) {
    __shared__ int h[2][MAXBKT], lbase[2][MAXBKT], lcur[2][MAXBKT];
    const int t = threadIdx.x;
    const int half = t >> 7;
    for (int i = t; i < 2 * MAXBKT; i += 256) ((int*)h)[i] = 0;
    __syncthreads();
    const int E4 = E >> 2;   // E multiple of 4
    const int4* s4p = (const int4*)src;
    const int4* d4p = (const int4*)dst;
    int4 sv[4], dv[4]; bool ok[4];
#pragma unroll
    for (int r = 0; r < 4; r++) {
        int i4 = blockIdx.x * 1024 + r * 256 + t;
        ok[r] = (i4 < E4);
        if (ok[r]) {
            sv[r] = s4p[i4]; dv[r] = d4p[i4];
            atomicAdd(&h[half][dv[r].x >> NBKT_SHIFT], 1);
            atomicAdd(&h[half][dv[r].y >> NBKT_SHIFT], 1);
            atomicAdd(&h[half][dv[r].z >> NBKT_SHIFT], 1);
            atomicAdd(&h[half][dv[r].w >> NBKT_SHIFT], 1);
        }
    }
    __syncthreads();
    for (int i = t; i < 2 * nbkt; i += 256) {
        const int hh = (i >= nbkt) ? 1 : 0;
        const int b = hh ? (i - nbkt) : i;
        const int c = h[hh][b];
        lbase[hh][b] = c ? ((b << CAP_SHIFT) + atomicAdd(&bcur[b], c)) : 0;
        lcur[hh][b] = 0;
    }
    __syncthreads();
#pragma unroll
    for (int r = 0; r < 4; r++) {
        if (!ok[r]) continue;
        int ss[4] = {sv[r].x, sv[r].y, sv[r].z, sv[r].w};
        int dd[4] = {dv[r].x, dv[r].y, dv[r].z, dv[r].w};
#pragma unroll
        for (int j = 0; j < 4; j++) {
            int b = dd[j] >> NBKT_SHIFT;
            int p = atomicAdd(&lcur[half][b], 1);
            bktA[(size_t)lbase[half][b] + p] =
                ((unsigned)ss[j] << NBKT_SHIFT) | (unsigned)(dd[j] & (BKT_NODES - 1));
        }
    }
}

// merged per-bucket: degree count -> wave scan (PADDED to mult of 8) -> rowinfo/dinv ->
// LDS-sorted CSR fill; padding slots point at the zero row (index N).

__launch_bounds__(512)
__global__ void k_build(const unsigned* __restrict__ bktA, const int* __restrict__ bcur,
                        int2* __restrict__ rowinfo, float* __restrict__ dinv,
                        int* __restrict__ csr_src, int N) {
    __shared__ int sorted[BKT_CAP];      // 32 KB
    __shared__ int cnt[BKT_NODES];
    __shared__ int cur[BKT_NODES];
    __shared__ int wpart[4], wbase[4];
    __shared__ int stot;
    const int t = threadIdx.x;
    const int b = blockIdx.x;
    const int nb = b << NBKT_SHIFT;
    if (t < BKT_NODES) cnt[t] = 0;
    __syncthreads();
    const int beg = b << CAP_SHIFT;
    const int tot = bcur[b];
    // pass 1: histogram (coalesced global read)
    for (int i = t; i < tot; i += 512)
        atomicAdd(&cnt[bktA[beg + i] & (BKT_NODES - 1)], 1);
    __syncthreads();
    // scan over 256 padded counters (4 waves)
    const int lane = t & 63, wv = t >> 6;
    int my = 0, pm = 0, x = 0;
    if (t < BKT_NODES) {
        my = cnt[t];
        pm = (my + 7) & ~7;        // pad each row to multiple of 8
        x = pm;
#pragma unroll
        for (int off = 1; off < 64; off <<= 1) {
            int y = __shfl_up(x, off, 64);
            if (lane >= off) x += y;
        }
        if (lane == 63) wpart[wv] = x;
    }
    __syncthreads();
    if (t == 0) {
        int s = 0;
        for (int w = 0; w < 4; w++) { int tmp = wpart[w]; wbase[w] = s; s += tmp; }
    }
    __syncthreads();
    if (t < BKT_NODES) {
        const int incl = x + wbase[wv];
        const int rbeg = incl - pm;          // local exclusive prefix (padded layout)
        cur[t] = rbeg;
        const int n = nb + t;
        if (n < N) {
            rowinfo[n] = make_int2(beg + rbeg, pm);
            dinv[n] = rsqrtf((float)(my + 1));  // +1 self-loop (TRUE degree)
        }
        for (int i = rbeg + my; i < rbeg + pm; i++) sorted[i] = N;  // zero-row pads
        if (t == BKT_NODES - 1) stot = incl;
    }
    __syncthreads();
    // pass 2: scatter into LDS (global re-read is L2-hot), then coalesced dump
    for (int i = t; i < tot; i += 512) {
        unsigned pr = bktA[beg + i];
        int d = pr & (BKT_NODES - 1);
        int p = atomicAdd(&cur[d], 1);
        sorted[p] = (int)(pr >> NBKT_SHIFT);
    }
    __syncthreads();
    const int tp = stot;
    for (int i = t; i < tp; i += 512)
        csr_src[beg + i] = sorted[i];
}

// ---------------- W prep: layer0 -> bf16 Wt_b[n][k]; layers 1,2 -> fp8 Wt8 ----------------
// Also zeroes gsums, bcur, and the zero-row (index N) of both fp8 node buffers.

__global__ void k_prep_w(const float* __restrict__ Wa, const float* __restrict__ Wb,
                         const float* __restrict__ Wc, ushort* __restrict__ Wt_b,
                         unsigned char* __restrict__ Wt8, float* __restrict__ gsums,
                         int* __restrict__ bcur, unsigned char* __restrict__ B0q,
                         unsigned char* __restrict__ B1q, int N) {
    int idx = blockIdx.x * 256 + threadIdx.x;  // 192*256 = 49152 = 3*16384
    int layer = idx >> 14;
    int r = idx & 16383;
    int nn = r >> 7, kk = r & 127;
    if (layer == 0) {
        Wt_b[r] = f2bf(Wa[kk * 128 + nn]);
    } else {
        const float* W = (layer == 1) ? Wb : Wc;
        Wt8[(size_t)(layer - 1) * 16384 + r] = f2fp8(W[kk * 128 + nn]);
    }
    if (idx < 8192) gsums[idx] = 0.f;
    if (idx < MAXBKT) bcur[idx] = 0;
    uint4 z = {0, 0, 0, 0};
    if (idx < 8) ((uint4*)(B0q + (size_t)N * FDIM))[idx] = z;
    else if (idx < 16) ((uint4*)(B1q + (size_t)N * FDIM))[idx - 8] = z;
}

// ---------------- layer-1 MFMA GEMM (bf16): xs(fp8) = dinv .* (X_f32 @ W) ----------------

__launch_bounds__(256)
__global__ void k_gemm_f32(const float* __restrict__ X, const ushort* __restrict__ Wt,
                           const float* __restrict__ dinv, unsigned char* __restrict__ C,
                           int N) {
    __shared__ __align__(16) ushort As[128][136];
    __shared__ ushort Ws[128][136];
    const int t = threadIdx.x;
    const int row0 = blockIdx.x * 128;

#pragma unroll
    for (int i = 0; i < 8; i++) {
        int c = t + i * 256;
        int r = c >> 4, c8 = (c & 15) * 8;
        *(bf16x8*)&Ws[r][c8] = *(const bf16x8*)&Wt[r * 128 + c8];
    }
#pragma unroll
    for (int i = 0; i < 8; i++) {
        int c = t + i * 256;
        int r = c >> 4, c8 = (c & 15) * 8;
        int row = row0 + r;
        bf16x8 pk = {0, 0, 0, 0, 0, 0, 0, 0};
        if (row < N) {
            const float* sp = X + (size_t)row * FDIM + c8;
            float4 u0 = *(const float4*)(sp);
            float4 u1 = *(const float4*)(sp + 4);
            union { unsigned u[4]; bf16x8 v; } cv;
            cv.u[0] = cvt_pk_bf16(u0.x, u0.y);
            cv.u[1] = cvt_pk_bf16(u0.z, u0.w);
            cv.u[2] = cvt_pk_bf16(u1.x, u1.y);
            cv.u[3] = cvt_pk_bf16(u1.z, u1.w);
            pk = cv.v;
        }
        *(bf16x8*)&As[r][c8] = pk;
    }
    __syncthreads();

    const int w = t >> 6, l = t & 63;
    const int m = l & 15, q = l >> 4;
    const int r0 = w * 32;

    bf16x8 a0[4], a1[4];
#pragma unroll
    for (int ks = 0; ks < 4; ks++) {
        a0[ks] = *(const bf16x8*)&As[r0 + m][ks * 32 + q * 8];
        a1[ks] = *(const bf16x8*)&As[r0 + 16 + m][ks * 32 + q * 8];
    }

    f32x4 acc0[8], acc1[8];
#pragma unroll
    for (int ct = 0; ct < 8; ct++) { acc0[ct] = {0, 0, 0, 0}; acc1[ct] = {0, 0, 0, 0}; }

#pragma unroll
    for (int ct = 0; ct < 8; ct++) {
#pragma unroll
        for (int ks = 0; ks < 4; ks++) {
            bf16x8 b = *(const bf16x8*)&Ws[ct * 16 + m][ks * 32 + q * 8];
            acc0[ct] = __builtin_amdgcn_mfma_f32_16x16x32_bf16(a0[ks], b, acc0[ct], 0, 0, 0);
            acc1[ct] = __builtin_amdgcn_mfma_f32_16x16x32_bf16(a1[ks], b, acc1[ct], 0, 0, 0);
        }
    }

    float dv0[4], dv1[4];
#pragma unroll
    for (int r = 0; r < 4; r++) {
        int row = row0 + r0 + q * 4 + r;
        dv0[r] = (row < N) ? dinv[row] : 0.f;
        dv1[r] = (row + 16 < N) ? dinv[row + 16] : 0.f;
    }

    // stage fp8 tile into LDS (reuse As), then coalesced 16-B stores
    __syncthreads();
    char* Ab = (char*)&As[0][0];
#pragma unroll
    for (int ct = 0; ct < 8; ct++) {
#pragma unroll
        for (int r = 0; r < 4; r++) {
            int rl = r0 + q * 4 + r;
            Ab[rl * 128 + ct * 16 + m] = (char)f2fp8(acc0[ct][r] * dv0[r]);
            Ab[(rl + 16) * 128 + ct * 16 + m] = (char)f2fp8(acc1[ct][r] * dv1[r]);
        }
    }
    __syncthreads();
    const uint4* As4 = (const uint4*)Ab;
#pragma unroll
    for (int i = 0; i < 4; i++) {
        int c = t + i * 256;
        int row = c >> 3;
        int col = (c & 7) * 16;
        int grow = row0 + row;
        if (grow < N) *(uint4*)&C[(size_t)grow * FDIM + col] = As4[c];
    }
}

// ---------------- layers 2/3 MFMA GEMM (fp8 x fp8): xs(fp8) = dinv .* (A_fp8 @ W_fp8) ----
// A/W tiles staged via async global_load_lds (16 B/lane) with both-sides XOR swizzle:
// global source column pre-swizzled (col = 16*((l&7)^(l>>3))), LDS linear, reads XOR
// ((row&7)<<4). Read bank = (ks*8+q*2)^((m&7)<<2): 4 lanes/bank (parity with +16 pad).

__launch_bounds__(256)
__global__ void k_gemm_fp8(const unsigned char* __restrict__ X,
                           const unsigned char* __restrict__ W8,
                           const float* __restrict__ dinv, unsigned char* __restrict__ C,
                           int N) {
    __shared__ __align__(16) unsigned char As[128 * 128];
    __shared__ __align__(16) unsigned char Ws[128 * 128];
    const int t = threadIdx.x;
    const int w = t >> 6, l = t & 63;
    const int row0 = blockIdx.x * 128;

    // async stage: each wave covers rows w*32 .. w*32+31 of both tiles (4 iters x 8 rows).
    // Per-lane GLOBAL addr carries the inverse swizzle; LDS dest is linear (lane*16).
    {
        const int lrow = l >> 3;                     // row within 8-row chunk; == row&7
        const int scol = ((l & 7) ^ lrow) << 4;      // inverse-swizzled 16-B column
        const unsigned char* gx = X + (size_t)(row0 + w * 32 + lrow) * FDIM + scol;
        const unsigned char* gw = W8 + (size_t)(w * 32 + lrow) * FDIM + scol;
#pragma unroll
        for (int i = 0; i < 4; i++) {
            gload16(gx + (size_t)i * 8 * FDIM, &As[(w * 32 + i * 8) * FDIM]);
            gload16(gw + (size_t)i * 8 * FDIM, &Ws[(w * 32 + i * 8) * FDIM]);
        }
    }
    __syncthreads();   // drains vmcnt (incl. global_load_lds) before LDS reads

    const int m = l & 15, q = l >> 4;
    const int r0 = w * 32;
    const int xa = (m & 7) << 4;    // read-side swizzle (row&7 == m&7 for all fragment rows)

    i64 a0[4], a1[4];
#pragma unroll
    for (int ks = 0; ks < 4; ks++) {
        a0[ks] = *(const i64*)&As[(r0 + m) * FDIM + ((ks * 32 + q * 8) ^ xa)];
        a1[ks] = *(const i64*)&As[(r0 + 16 + m) * FDIM + ((ks * 32 + q * 8) ^ xa)];
    }

    f32x4 acc0[8], acc1[8];
#pragma unroll
    for (int ct = 0; ct < 8; ct++) { acc0[ct] = {0, 0, 0, 0}; acc1[ct] = {0, 0, 0, 0}; }

#pragma unroll
    for (int ct = 0; ct < 8; ct++) {
#pragma unroll
        for (int ks = 0; ks < 4; ks++) {
            i64 b = *(const i64*)&Ws[(ct * 16 + m) * FDIM + ((ks * 32 + q * 8) ^ xa)];
            acc0[ct] = __builtin_amdgcn_mfma_f32_16x16x32_fp8_fp8(a0[ks], b, acc0[ct], 0, 0, 0);
            acc1[ct] = __builtin_amdgcn_mfma_f32_16x16x32_fp8_fp8(a1[ks], b, acc1[ct], 0, 0, 0);
        }
    }

    float dv0[4], dv1[4];
#pragma unroll
    for (int r = 0; r < 4; r++) {
        int row = row0 + r0 + q * 4 + r;
        dv0[r] = (row < N) ? dinv[row] : 0.f;
        dv1[r] = (row + 16 < N) ? dinv[row + 16] : 0.f;
    }

    __syncthreads();
    char* Ab = (char*)&As[0];
#pragma unroll
    for (int ct = 0; ct < 8; ct++) {
#pragma unroll
        for (int r = 0; r < 4; r++) {
            int rl = r0 + q * 4 + r;
            Ab[rl * 128 + ct * 16 + m] = (char)f2fp8(acc0[ct][r] * dv0[r]);
            Ab[(rl + 16) * 128 + ct * 16 + m] = (char)f2fp8(acc1[ct][r] * dv1[r]);
        }
    }
    __syncthreads();
    const uint4* As4 = (const uint4*)Ab;
#pragma unroll
    for (int i = 0; i < 4; i++) {
        int c = t + i * 256;
        int row = c >> 3;
        int col = (c & 7) * 16;
        int grow = row0 + row;
        if (grow < N) *(uint4*)&C[(size_t)grow * FDIM + col] = As4[c];
    }
}

// ---------------- fused pull-aggregate, one node per wave64, fp8 in / fp8 out ----------------
// NEW: neighbor rows gathered via global_load_lds — one instruction stages 8 rows
// (per-lane global addr, wave-uniform LDS dest). 32-edge chunks (4 KB/wave buffer),
// XOR-swizzled source/read (conflict-free ds_read_b64). Degrees padded to mult of 8.

__launch_bounds__(256)
__global__ void k_aggregate(const unsigned char* __restrict__ xs8,
                            const int2* __restrict__ rowinfo,
                            const int* __restrict__ csr_src, const float* __restrict__ dinv,
                            const float* __restrict__ bias, unsigned char* __restrict__ out,
                            int N, int do_relu) {
    __shared__ __align__(16) unsigned char stage[4][32 * FDIM];   // 4 waves x 4 KB
    const int wv = threadIdx.x >> 6;
    const int n = (blockIdx.x << 2) + wv;
    if (n >= N) return;
    const int l = threadIdx.x & 63;
    const int fl = l & 15;      // feature slot: features fl*8 .. fl*8+7
    const int grp = l >> 4;     // row group 0..3
    const unsigned foff = (unsigned)fl << 3;   // byte offset within a 128-B row
    unsigned char* sb = stage[wv];

    f32x2 acc[4] = {{0, 0}, {0, 0}, {0, 0}, {0, 0}};
    if (grp == 0) {
        uint2 sv = *(const uint2*)(xs8 + (((unsigned)n << 7) | foff));
        fp8x8_add(sv, acc);
    }

    const int2 ri = rowinfo[n];
    const int beg = ri.x;
    const int deg = ri.y;       // padded: multiple of 8 (0 if isolated)

    // staging geometry: stage-inst i covers rows 8i..8i+7; lane l serves row 8i+(l>>3),
    // global 16-B chunk (l&7)^(l>>3)  ->  LDS[row][p] = global chunk p^(row&7).
    const int srow = l >> 3;                         // 0..7
    const unsigned schunk = ((unsigned)(l & 7) ^ (unsigned)srow) << 4;

    // consume swizzle: row r, slot fl reads LDS chunk (fl>>1)^(r&7)
    const unsigned rbase = ((unsigned)(fl >> 1) << 4) | ((unsigned)(fl & 1) << 3);

    for (int base = 0; base < deg; base += 32) {
        const int m = min(32, deg - base);   // multiple of 8
        int idx = 0;
        if (l < m) idx = csr_src[(unsigned)(beg + base + l)];  // coalesced (lanes 0..31)
        const int nst = m >> 3;
        for (int i = 0; i < nst; i++) {
            int s = __shfl(idx, i * 8 + srow, 64);
            const unsigned char* g = xs8 + (((size_t)(unsigned)s) << 7) + schunk;
            gload16(g, sb + i * 1024);
        }
        asm volatile("s_waitcnt vmcnt(0)" ::: "memory");
        __builtin_amdgcn_sched_barrier(0);
#pragma unroll 2
        for (int j = 0; j < m; j += 4) {
            int r = j + grp;
            unsigned off = ((unsigned)r << 7) | (rbase ^ (((unsigned)r & 7) << 4));
            uint2 v = *(const uint2*)(sb + off);     // ds_read_b64, conflict-free
            fp8x8_add(v, acc);
        }
    }

    float a[8] = {acc[0][0], acc[0][1], acc[1][0], acc[1][1],
                  acc[2][0], acc[2][1], acc[3][0], acc[3][1]};
#pragma unroll
    for (int k = 0; k < 8; k++) {
        a[k] += __shfl_xor(a[k], 16, 64);
        a[k] += __shfl_xor(a[k], 32, 64);
    }

    if (grp == 0) {
        const float d = dinv[n];
        const float4 b0 = ((const float4*)bias)[fl * 2];
        const float4 b1 = ((const float4*)bias)[fl * 2 + 1];
        const float bb[8] = {b0.x, b0.y, b0.z, b0.w, b1.x, b1.y, b1.z, b1.w};
        float v[8];
#pragma unroll
        for (int k = 0; k < 8; k++) {
            v[k] = d * a[k] + bb[k];
            if (do_relu) v[k] = fmaxf(v[k], 0.f);
        }
        uint2 o;
        unsigned d0 = __builtin_amdgcn_cvt_pk_fp8_f32(v[0], v[1], 0u, false);
        o.x = __builtin_amdgcn_cvt_pk_fp8_f32(v[2], v[3], d0, true);
        unsigned d1 = __builtin_amdgcn_cvt_pk_fp8_f32(v[4], v[5], 0u, false);
        o.y = __builtin_amdgcn_cvt_pk_fp8_f32(v[6], v[7], d1, true);
        ((uint2*)out)[(size_t)n * 16 + fl] = o;
    }
}

// ---------------- pool (fp8 input): 8 lane-groups x 32-node serial runs ----------------

__launch_bounds__(256)
__global__ void k_pool(const unsigned char* __restrict__ x3, const int* __restrict__ batch,
                       float* __restrict__ sums, int N) {
    const int t = threadIdx.x;
    const int fq = t & 31;              // feature quad: features 4*fq .. 4*fq+3
    const int sub = t >> 5;             // node lane 0..7
    const int n0 = blockIdx.x * 256 + sub * 32;
    if (n0 >= N) return;
    const int n1 = (n0 + 32 < N) ? n0 + 32 : N;

    f32x4 acc = {0.f, 0.f, 0.f, 0.f};
    int cur = batch[n0];
    for (int n = n0; n < n1; n++) {
        int g = batch[n];
        if (g != cur) {
            float* s = &sums[cur * FDIM + (fq << 2)];
            atomicAdd(s + 0, acc[0]); atomicAdd(s + 1, acc[1]);
            atomicAdd(s + 2, acc[2]); atomicAdd(s + 3, acc[3]);
            acc = (f32x4){0.f, 0.f, 0.f, 0.f};
            cur = g;
        }
        unsigned w = *(const unsigned*)(x3 + ((size_t)n << 7) + (fq << 2));
        f32x2 lo = __builtin_amdgcn_cvt_pk_f32_fp8(w, false);
        f32x2 hi = __builtin_amdgcn_cvt_pk_f32_fp8(w, true);
        acc[0] += lo[0]; acc[1] += lo[1]; acc[2] += hi[0]; acc[3] += hi[1];
    }
    float* s = &sums[cur * FDIM + (fq << 2)];
    atomicAdd(s + 0, acc[0]); atomicAdd(s + 1, acc[1]);
    atomicAdd(s + 2, acc[2]); atomicAdd(s + 3, acc[3]);
}

// ---------------- per-graph mean + MLP + LayerNorm ----------------

__launch_bounds__(128)
__global__ void k_final(const float* __restrict__ sums, const int* __restrict__ batch, int N,
                        const float* __restrict__ Wm1, const float* __restrict__ bm1,
                        const float* __restrict__ Wm2, const float* __restrict__ bm2,
                        const float* __restrict__ ln_g, const float* __restrict__ ln_b,
                        float* __restrict__ out) {
    const int g = blockIdx.x;
    const int t = threadIdx.x;

    int lo = 0, hi = N;
    while (lo < hi) { int mid = (lo + hi) >> 1; if (batch[mid] < g) lo = mid + 1; else hi = mid; }
    int lo2 = lo, hi2 = N;
    while (lo2 < hi2) { int mid = (lo2 + hi2) >> 1; if (batch[mid] < g + 1) lo2 = mid + 1; else hi2 = mid; }
    float cnt = (float)(lo2 - lo);

    float gl = sums[g * FDIM + t] / fmaxf(cnt, 1.0f);

    __shared__ float gbuf[FDIM];
    __shared__ float hbuf[FDIM];
    __shared__ float wsum[4];
    gbuf[t] = gl;
    __syncthreads();

    float h = bm1[t];
#pragma unroll 8
    for (int k = 0; k < FDIM; k++) h += gbuf[k] * Wm1[k * FDIM + t];
    h = fmaxf(h, 0.f);
    hbuf[t] = h;
    __syncthreads();

    float y = bm2[t];
#pragma unroll 8
    for (int k = 0; k < FDIM; k++) y += hbuf[k] * Wm2[k * FDIM + t];

    float s = y, s2 = y * y;
#pragma unroll
    for (int off = 32; off > 0; off >>= 1) {
        s += __shfl_down(s, off, 64);
        s2 += __shfl_down(s2, off, 64);
    }
    if ((t & 63) == 0) { wsum[t >> 6] = s; wsum[2 + (t >> 6)] = s2; }
    __syncthreads();
    float sum = wsum[0] + wsum[1];
    float sumsq = wsum[2] + wsum[3];
    float mu = sum * (1.0f / FDIM);
    float var = sumsq * (1.0f / FDIM) - mu * mu;
    float r = rsqrtf(var + LN_EPS);
    out[g * FDIM + t] = (y - mu) * r * ln_g[t] + ln_b[t];
}

// ---------------- launch ----------------

extern "C" void kernel_launch(void* const* d_in, const int* in_sizes, int n_in,
                              void* d_out, int out_size, void* d_ws, size_t ws_size,
                              hipStream_t stream) {
    const float* x_in  = (const float*)d_in[0];
    const int*   eidx  = (const int*)d_in[1];
    const int*   batch = (const int*)d_in[2];
    const float* W1 = (const float*)d_in[3];
    const float* b1 = (const float*)d_in[4];
    const float* W2 = (const float*)d_in[5];
    const float* b2 = (const float*)d_in[6];
    const float* W3 = (const float*)d_in[7];
    const float* b3 = (const float*)d_in[8];
    const float* Wm1 = (const float*)d_in[9];
    const float* bm1 = (const float*)d_in[10];
    const float* Wm2 = (const float*)d_in[11];
    const float* bm2 = (const float*)d_in[12];
    const float* ln_g = (const float*)d_in[13];
    const float* ln_b = (const float*)d_in[14];
    float* out = (float*)d_out;

    const int N = in_sizes[0] / FDIM;   // 100000
    const int E = in_sizes[1] / 2;      // 1600000
    const int G = out_size / FDIM;      // 64

    const int* src = eidx;
    const int* dst = eidx + E;

    const int nbkt = (N + BKT_NODES - 1) >> NBKT_SHIFT;        // 391

    // workspace layout (B0q/B1q have one extra zero row at index N)
    char* p = (char*)d_ws;
    unsigned* bktA = (unsigned*)p;    p += (size_t)nbkt * BKT_CAP * 4;   // 12.8 MB (packed)
    unsigned char* B0q = (unsigned char*)p; p += (size_t)(N + 1) * FDIM; // 12.8 MB (fp8 xs)
    unsigned char* B1q = (unsigned char*)p; p += (size_t)(N + 1) * FDIM; // 12.8 MB (fp8 agg)
    int* csr_src = (int*)p;           p += (size_t)nbkt * BKT_CAP * 4;   // 12.8 MB
    int2* rowinfo = (int2*)p;         p += (size_t)N * 8;
    float* dinv = (float*)p;          p += (size_t)N * 4;
    ushort* Wt_b = (ushort*)p;        p += 16384 * 2;
    unsigned char* Wt8 = (unsigned char*)p; p += 2 * 16384;
    float* gsums = (float*)p;         p += (size_t)G * FDIM * 4;
    int* bcur = (int*)p;              p += MAXBKT * 4;

    const int TPB = 256;
    dim3 blk(TPB);
    dim3 gAgg((N + 3) / 4);
    dim3 gTile((N + 127) / 128);
    const int nEb = (E + 4095) / 4096;

    // ---- prep (also zeroes gsums/bcur/zero-rows) + build ----
    k_prep_w<<<dim3(192), blk, 0, stream>>>(W1, W2, W3, Wt_b, Wt8, gsums, bcur, B0q, B1q, N);
    k_bkt_scatter<<<dim3(nEb), blk, 0, stream>>>(src, dst, bcur, bktA, E, nbkt);
    k_build<<<dim3(nbkt), dim3(512), 0, stream>>>(bktA, bcur, rowinfo, dinv, csr_src, N);

    // ---- layer 1 (fp32 input, bf16 MFMA) ----
    k_gemm_f32<<<gTile, blk, 0, stream>>>(x_in, Wt_b, dinv, B0q, N);
    k_aggregate<<<gAgg, blk, 0, stream>>>(B0q, rowinfo, csr_src, dinv, b1, B1q, N, 1);

    // ---- layer 2 (fp8 MFMA) ----
    k_gemm_fp8<<<gTile, blk, 0, stream>>>(B1q, Wt8, dinv, B0q, N);
    k_aggregate<<<gAgg, blk, 0, stream>>>(B0q, rowinfo, csr_src, dinv, b2, B1q, N, 1);

    // ---- layer 3 (fp8 MFMA, no relu) ----
    k_gemm_fp8<<<gTile, blk, 0, stream>>>(B1q, Wt8 + 16384, dinv, B0q, N);
    k_aggregate<<<gAgg, blk, 0, stream>>>(B0q, rowinfo, csr_src, dinv, b3, B1q, N, 0);

    // ---- pool + MLP + LN ----
    k_pool<<<dim3((N + 255) / 256), blk, 0, stream>>>(B1q, batch, gsums, N);
    k_final<<<dim3(G), dim3(FDIM), 0, stream>>>(gsums, batch, N, Wm1, bm1, Wm2, bm2,
                                                ln_g, ln_b, out);
}

// Round 9
// 370.136 us; speedup vs baseline: 1.2298x; 1.0072x over previous
//
#include <hip/hip_runtime.h>

#define FDIM 128
#define LN_EPS 1e-5f
#define NBKT_SHIFT 8           // 256 nodes per bucket
#define BKT_NODES 256
#define MAXBKT 512             // supports N <= 131072
#define CAP_SHIFT 13           // 8192 edge capacity per bucket (mean 4096+pad, ~40 sigma)
#define BKT_CAP 8192

typedef short bf16x8 __attribute__((ext_vector_type(8)));
typedef float f32x4 __attribute__((ext_vector_type(4)));
typedef float f32x2 __attribute__((ext_vector_type(2)));
typedef ushort u16x8 __attribute__((ext_vector_type(8)));
typedef unsigned long long u64;
typedef long long i64;

static __device__ __forceinline__ ushort f2bf(float f) {
    union { float f; unsigned u; } v; v.f = f;
    unsigned r = v.u + 0x7FFFu + ((v.u >> 16) & 1u);  // RNE
    return (ushort)(r >> 16);
}
// packed f32x2 -> bf16x2 (RNE), single HW instruction
static __device__ __forceinline__ unsigned cvt_pk_bf16(float lo, float hi) {
    unsigned r;
    asm("v_cvt_pk_bf16_f32 %0, %1, %2" : "=v"(r) : "v"(lo), "v"(hi));
    return r;
}
// fp8 e4m3 (OCP on gfx950) encode/decode via HW converts
static __device__ __forceinline__ unsigned char f2fp8(float f) {
    return (unsigned char)__builtin_amdgcn_cvt_pk_fp8_f32(f, f, 0u, false);
}
static __device__ __forceinline__ float fp8tof(unsigned char b) {
    f32x2 p = __builtin_amdgcn_cvt_pk_f32_fp8((unsigned)b, false);
    return p[0];
}
static __device__ __forceinline__ void fp8x8_add(uint2 w, f32x2* acc) {
    acc[0] += __builtin_amdgcn_cvt_pk_f32_fp8(w.x, false);
    acc[1] += __builtin_amdgcn_cvt_pk_f32_fp8(w.x, true);
    acc[2] += __builtin_amdgcn_cvt_pk_f32_fp8(w.y, false);
    acc[3] += __builtin_amdgcn_cvt_pk_f32_fp8(w.y, true);
}

// async global->LDS, 16 B per lane (wave-uniform LDS base + lane*16)
typedef __attribute__((address_space(3))) unsigned char lds_uchar;
typedef const __attribute__((address_space(1))) unsigned char glob_uchar;
static __device__ __forceinline__ void gload16(const unsigned char* g, unsigned char* l) {
    __builtin_amdgcn_global_load_lds((glob_uchar*)g, (lds_uchar*)l, 16, 0, 0);
}

// ---------------- bucketed edge scatter (fixed-capacity buckets) ----------------
// 4096 edges/block. Packs (src,local_dst) into one u32: src<<8 | (dst & 255).

__launch_bounds__(256)
__global__ void k_bkt_scatter(const int* __restrict__ src, const int* __restrict__ dst,
                              int* __restrict__ bcur, unsigned* __restrict__ bktA,
                              int E, int nbkt) {
    __shared__ int h[2][MAXBKT], lbase[2][MAXBKT], lcur[2][MAXBKT];
    const int t = threadIdx.x;
    const int half = t >> 7;
    for (int i = t; i < 2 * MAXBKT; i += 256) ((int*)h)[i] = 0;
    __syncthreads();
    const int E4 = E >> 2;   // E multiple of 4
    const int4* s4p = (const int4*)src;
    const int4* d4p = (const int4*)dst;
    int4 sv[4], dv[4]; bool ok[4];
#pragma unroll
    for (int r = 0; r < 4; r++) {
        int i4 = blockIdx.x * 1024 + r * 256 + t;
        ok[r] = (i4 < E4);
        if (ok[r]) {
            sv[r] = s4p[i4]; dv[r] = d4p[i4];
            atomicAdd(&h[half][dv[r].x >> NBKT_SHIFT], 1);
            atomicAdd(&h[half][dv[r].y >> NBKT_SHIFT], 1);
            atomicAdd(&h[half][dv[r].z >> NBKT_SHIFT], 1);
            atomicAdd(&h[half][dv[r].w >> NBKT_SHIFT], 1);
        }
    }
    __syncthreads();
    for (int i = t; i < 2 * nbkt; i += 256) {
        const int hh = (i >= nbkt) ? 1 : 0;
        const int b = hh ? (i - nbkt) : i;
        const int c = h[hh][b];
        lbase[hh][b] = c ? ((b << CAP_SHIFT) + atomicAdd(&bcur[b], c)) : 0;
        lcur[hh][b] = 0;
    }
    __syncthreads();
#pragma unroll
    for (int r = 0; r < 4; r++) {
        if (!ok[r]) continue;
        int ss[4] = {sv[r].x, sv[r].y, sv[r].z, sv[r].w};
        int dd[4] = {dv[r].x, dv[r].y, dv[r].z, dv[r].w};
#pragma unroll
        for (int j = 0; j < 4; j++) {
            int b = dd[j] >> NBKT_SHIFT;
            int p = atomicAdd(&lcur[half][b], 1);
            bktA[(size_t)lbase[half][b] + p] =
                ((unsigned)ss[j] << NBKT_SHIFT) | (unsigned)(dd[j] & (BKT_NODES - 1));
        }
    }
}

// merged per-bucket: degree count -> wave scan (PADDED to mult of 8) -> rowinfo/dinv ->
// LDS-sorted CSR fill; padding slots point at the zero row (index N).

__launch_bounds__(512)
__global__ void k_build(const unsigned* __restrict__ bktA, const int* __restrict__ bcur,
                        int2* __restrict__ rowinfo, float* __restrict__ dinv,
                        int* __restrict__ csr_src, int N) {
    __shared__ int sorted[BKT_CAP];      // 32 KB
    __shared__ int cnt[BKT_NODES];
    __shared__ int cur[BKT_NODES];
    __shared__ int wpart[4], wbase[4];
    __shared__ int stot;
    const int t = threadIdx.x;
    const int b = blockIdx.x;
    const int nb = b << NBKT_SHIFT;
    if (t < BKT_NODES) cnt[t] = 0;
    __syncthreads();
    const int beg = b << CAP_SHIFT;
    const int tot = bcur[b];
    // pass 1: histogram (coalesced global read)
    for (int i = t; i < tot; i += 512)
        atomicAdd(&cnt[bktA[beg + i] & (BKT_NODES - 1)], 1);
    __syncthreads();
    // scan over 256 padded counters (4 waves)
    const int lane = t & 63, wv = t >> 6;
    int my = 0, pm = 0, x = 0;
    if (t < BKT_NODES) {
        my = cnt[t];
        pm = (my + 7) & ~7;        // pad each row to multiple of 8
        x = pm;
#pragma unroll
        for (int off = 1; off < 64; off <<= 1) {
            int y = __shfl_up(x, off, 64);
            if (lane >= off) x += y;
        }
        if (lane == 63) wpart[wv] = x;
    }
    __syncthreads();
    if (t == 0) {
        int s = 0;
        for (int w = 0; w < 4; w++) { int tmp = wpart[w]; wbase[w] = s; s += tmp; }
    }
    __syncthreads();
    if (t < BKT_NODES) {
        const int incl = x + wbase[wv];
        const int rbeg = incl - pm;          // local exclusive prefix (padded layout)
        cur[t] = rbeg;
        const int n = nb + t;
        if (n < N) {
            rowinfo[n] = make_int2(beg + rbeg, pm);
            dinv[n] = rsqrtf((float)(my + 1));  // +1 self-loop (TRUE degree)
        }
        for (int i = rbeg + my; i < rbeg + pm; i++) sorted[i] = N;  // zero-row pads
        if (t == BKT_NODES - 1) stot = incl;
    }
    __syncthreads();
    // pass 2: scatter into LDS (global re-read is L2-hot), then coalesced dump
    for (int i = t; i < tot; i += 512) {
        unsigned pr = bktA[beg + i];
        int d = pr & (BKT_NODES - 1);
        int p = atomicAdd(&cur[d], 1);
        sorted[p] = (int)(pr >> NBKT_SHIFT);
    }
    __syncthreads();
    const int tp = stot;
    for (int i = t; i < tp; i += 512)
        csr_src[beg + i] = sorted[i];
}

// ---------------- W prep: layer0 -> bf16 Wt_b[n][k]; layers 1,2 -> fp8 Wt8 ----------------
// Also zeroes gsums, bcur, and the zero-row (index N) of both fp8 node buffers.

__global__ void k_prep_w(const float* __restrict__ Wa, const float* __restrict__ Wb,
                         const float* __restrict__ Wc, ushort* __restrict__ Wt_b,
                         unsigned char* __restrict__ Wt8, float* __restrict__ gsums,
                         int* __restrict__ bcur, unsigned char* __restrict__ B0q,
                         unsigned char* __restrict__ B1q, int N) {
    int idx = blockIdx.x * 256 + threadIdx.x;  // 192*256 = 49152 = 3*16384
    int layer = idx >> 14;
    int r = idx & 16383;
    int nn = r >> 7, kk = r & 127;
    if (layer == 0) {
        Wt_b[r] = f2bf(Wa[kk * 128 + nn]);
    } else {
        const float* W = (layer == 1) ? Wb : Wc;
        Wt8[(size_t)(layer - 1) * 16384 + r] = f2fp8(W[kk * 128 + nn]);
    }
    if (idx < 8192) gsums[idx] = 0.f;
    if (idx < MAXBKT) bcur[idx] = 0;
    uint4 z = {0, 0, 0, 0};
    if (idx < 8) ((uint4*)(B0q + (size_t)N * FDIM))[idx] = z;
    else if (idx < 16) ((uint4*)(B1q + (size_t)N * FDIM))[idx - 8] = z;
}

// ---------------- layer-1 MFMA GEMM (bf16): xs(fp8) = dinv .* (X_f32 @ W) ----------------

__launch_bounds__(256)
__global__ void k_gemm_f32(const float* __restrict__ X, const ushort* __restrict__ Wt,
                           const float* __restrict__ dinv, unsigned char* __restrict__ C,
                           int N) {
    __shared__ __align__(16) ushort As[128][136];
    __shared__ ushort Ws[128][136];
    const int t = threadIdx.x;
    const int row0 = blockIdx.x * 128;

#pragma unroll
    for (int i = 0; i < 8; i++) {
        int c = t + i * 256;
        int r = c >> 4, c8 = (c & 15) * 8;
        *(bf16x8*)&Ws[r][c8] = *(const bf16x8*)&Wt[r * 128 + c8];
    }
#pragma unroll
    for (int i = 0; i < 8; i++) {
        int c = t + i * 256;
        int r = c >> 4, c8 = (c & 15) * 8;
        int row = row0 + r;
        bf16x8 pk = {0, 0, 0, 0, 0, 0, 0, 0};
        if (row < N) {
            const float* sp = X + (size_t)row * FDIM + c8;
            float4 u0 = *(const float4*)(sp);
            float4 u1 = *(const float4*)(sp + 4);
            union { unsigned u[4]; bf16x8 v; } cv;
            cv.u[0] = cvt_pk_bf16(u0.x, u0.y);
            cv.u[1] = cvt_pk_bf16(u0.z, u0.w);
            cv.u[2] = cvt_pk_bf16(u1.x, u1.y);
            cv.u[3] = cvt_pk_bf16(u1.z, u1.w);
            pk = cv.v;
        }
        *(bf16x8*)&As[r][c8] = pk;
    }
    __syncthreads();

    const int w = t >> 6, l = t & 63;
    const int m = l & 15, q = l >> 4;
    const int r0 = w * 32;

    bf16x8 a0[4], a1[4];
#pragma unroll
    for (int ks = 0; ks < 4; ks++) {
        a0[ks] = *(const bf16x8*)&As[r0 + m][ks * 32 + q * 8];
        a1[ks] = *(const bf16x8*)&As[r0 + 16 + m][ks * 32 + q * 8];
    }

    f32x4 acc0[8], acc1[8];
#pragma unroll
    for (int ct = 0; ct < 8; ct++) { acc0[ct] = {0, 0, 0, 0}; acc1[ct] = {0, 0, 0, 0}; }

#pragma unroll
    for (int ct = 0; ct < 8; ct++) {
#pragma unroll
        for (int ks = 0; ks < 4; ks++) {
            bf16x8 b = *(const bf16x8*)&Ws[ct * 16 + m][ks * 32 + q * 8];
            acc0[ct] = __builtin_amdgcn_mfma_f32_16x16x32_bf16(a0[ks], b, acc0[ct], 0, 0, 0);
            acc1[ct] = __builtin_amdgcn_mfma_f32_16x16x32_bf16(a1[ks], b, acc1[ct], 0, 0, 0);
        }
    }

    float dv0[4], dv1[4];
#pragma unroll
    for (int r = 0; r < 4; r++) {
        int row = row0 + r0 + q * 4 + r;
        dv0[r] = (row < N) ? dinv[row] : 0.f;
        dv1[r] = (row + 16 < N) ? dinv[row + 16] : 0.f;
    }

    // stage fp8 tile into LDS (reuse As), then coalesced 16-B stores
    __syncthreads();
    char* Ab = (char*)&As[0][0];
#pragma unroll
    for (int ct = 0; ct < 8; ct++) {
#pragma unroll
        for (int r = 0; r < 4; r++) {
            int rl = r0 + q * 4 + r;
            Ab[rl * 128 + ct * 16 + m] = (char)f2fp8(acc0[ct][r] * dv0[r]);
            Ab[(rl + 16) * 128 + ct * 16 + m] = (char)f2fp8(acc1[ct][r] * dv1[r]);
        }
    }
    __syncthreads();
    const uint4* As4 = (const uint4*)Ab;
#pragma unroll
    for (int i = 0; i < 4; i++) {
        int c = t + i * 256;
        int row = c >> 3;
        int col = (c & 7) * 16;
        int grow = row0 + row;
        if (grow < N) *(uint4*)&C[(size_t)grow * FDIM + col] = As4[c];
    }
}

// ---------------- layers 2/3 MFMA GEMM (fp8 x fp8): xs(fp8) = dinv .* (A_fp8 @ W_fp8) ----
// A/W tiles staged via async global_load_lds (16 B/lane) with both-sides XOR swizzle:
// global source column pre-swizzled (col = 16*((l&7)^(l>>3))), LDS linear, reads XOR
// ((row&7)<<4). Read bank = (ks*8+q*2)^((m&7)<<2): 4 lanes/bank (parity with +16 pad).

__launch_bounds__(256)
__global__ void k_gemm_fp8(const unsigned char* __restrict__ X,
                           const unsigned char* __restrict__ W8,
                           const float* __restrict__ dinv, unsigned char* __restrict__ C,
                           int N) {
    __shared__ __align__(16) unsigned char As[128 * 128];
    __shared__ __align__(16) unsigned char Ws[128 * 128];
    const int t = threadIdx.x;
    const int w = t >> 6, l = t & 63;
    const int row0 = blockIdx.x * 128;

    // async stage: each wave covers rows w*32 .. w*32+31 of both tiles (4 iters x 8 rows).
    // Per-lane GLOBAL addr carries the inverse swizzle; LDS dest is linear (lane*16).
    {
        const int lrow = l >> 3;                     // row within 8-row chunk; == row&7
        const int scol = ((l & 7) ^ lrow) << 4;      // inverse-swizzled 16-B column
        const unsigned char* gx = X + (size_t)(row0 + w * 32 + lrow) * FDIM + scol;
        const unsigned char* gw = W8 + (size_t)(w * 32 + lrow) * FDIM + scol;
#pragma unroll
        for (int i = 0; i < 4; i++) {
            gload16(gx + (size_t)i * 8 * FDIM, &As[(w * 32 + i * 8) * FDIM]);
            gload16(gw + (size_t)i * 8 * FDIM, &Ws[(w * 32 + i * 8) * FDIM]);
        }
    }
    __syncthreads();   // drains vmcnt (incl. global_load_lds) before LDS reads

    const int m = l & 15, q = l >> 4;
    const int r0 = w * 32;
    const int xa = (m & 7) << 4;    // read-side swizzle (row&7 == m&7 for all fragment rows)

    i64 a0[4], a1[4];
#pragma unroll
    for (int ks = 0; ks < 4; ks++) {
        a0[ks] = *(const i64*)&As[(r0 + m) * FDIM + ((ks * 32 + q * 8) ^ xa)];
        a1[ks] = *(const i64*)&As[(r0 + 16 + m) * FDIM + ((ks * 32 + q * 8) ^ xa)];
    }

    f32x4 acc0[8], acc1[8];
#pragma unroll
    for (int ct = 0; ct < 8; ct++) { acc0[ct] = {0, 0, 0, 0}; acc1[ct] = {0, 0, 0, 0}; }

#pragma unroll
    for (int ct = 0; ct < 8; ct++) {
#pragma unroll
        for (int ks = 0; ks < 4; ks++) {
            i64 b = *(const i64*)&Ws[(ct * 16 + m) * FDIM + ((ks * 32 + q * 8) ^ xa)];
            acc0[ct] = __builtin_amdgcn_mfma_f32_16x16x32_fp8_fp8(a0[ks], b, acc0[ct], 0, 0, 0);
            acc1[ct] = __builtin_amdgcn_mfma_f32_16x16x32_fp8_fp8(a1[ks], b, acc1[ct], 0, 0, 0);
        }
    }

    float dv0[4], dv1[4];
#pragma unroll
    for (int r = 0; r < 4; r++) {
        int row = row0 + r0 + q * 4 + r;
        dv0[r] = (row < N) ? dinv[row] : 0.f;
        dv1[r] = (row + 16 < N) ? dinv[row + 16] : 0.f;
    }

    __syncthreads();
    char* Ab = (char*)&As[0];
#pragma unroll
    for (int ct = 0; ct < 8; ct++) {
#pragma unroll
        for (int r = 0; r < 4; r++) {
            int rl = r0 + q * 4 + r;
            Ab[rl * 128 + ct * 16 + m] = (char)f2fp8(acc0[ct][r] * dv0[r]);
            Ab[(rl + 16) * 128 + ct * 16 + m] = (char)f2fp8(acc1[ct][r] * dv1[r]);
        }
    }
    __syncthreads();
    const uint4* As4 = (const uint4*)Ab;
#pragma unroll
    for (int i = 0; i < 4; i++) {
        int c = t + i * 256;
        int row = c >> 3;
        int col = (c & 7) * 16;
        int grow = row0 + row;
        if (grow < N) *(uint4*)&C[(size_t)grow * FDIM + col] = As4[c];
    }
}

// ---------------- fused pull-aggregate, one node per wave64, fp8 in / fp8 out ----------------
// Neighbor rows gathered via global_load_lds — one instruction stages 8 rows
// (per-lane global addr, wave-uniform LDS dest). 32-edge chunks (4 KB/wave buffer),
// XOR-swizzled source/read (conflict-free ds_read_b64). Degrees padded to mult of 8.

__launch_bounds__(256)
__global__ void k_aggregate(const unsigned char* __restrict__ xs8,
                            const int2* __restrict__ rowinfo,
                            const int* __restrict__ csr_src, const float* __restrict__ dinv,
                            const float* __restrict__ bias, unsigned char* __restrict__ out,
                            int N, int do_relu) {
    __shared__ __align__(16) unsigned char stage[4][32 * FDIM];   // 4 waves x 4 KB
    const int wv = threadIdx.x >> 6;
    const int n = (blockIdx.x << 2) + wv;
    if (n >= N) return;
    const int l = threadIdx.x & 63;
    const int fl = l & 15;      // feature slot: features fl*8 .. fl*8+7
    const int grp = l >> 4;     // row group 0..3
    const unsigned foff = (unsigned)fl << 3;   // byte offset within a 128-B row
    unsigned char* sb = stage[wv];

    f32x2 acc[4] = {{0, 0}, {0, 0}, {0, 0}, {0, 0}};
    if (grp == 0) {
        uint2 sv = *(const uint2*)(xs8 + (((unsigned)n << 7) | foff));
        fp8x8_add(sv, acc);
    }

    const int2 ri = rowinfo[n];
    const int beg = ri.x;
    const int deg = ri.y;       // padded: multiple of 8 (0 if isolated)

    // staging geometry: stage-inst i covers rows 8i..8i+7; lane l serves row 8i+(l>>3),
    // global 16-B chunk (l&7)^(l>>3)  ->  LDS[row][p] = global chunk p^(row&7).
    const int srow = l >> 3;                         // 0..7
    const unsigned schunk = ((unsigned)(l & 7) ^ (unsigned)srow) << 4;

    // consume swizzle: row r, slot fl reads LDS chunk (fl>>1)^(r&7)
    const unsigned rbase = ((unsigned)(fl >> 1) << 4) | ((unsigned)(fl & 1) << 3);

    for (int base = 0; base < deg; base += 32) {
        const int m = min(32, deg - base);   // multiple of 8
        int idx = 0;
        if (l < m) idx = csr_src[(unsigned)(beg + base + l)];  // coalesced (lanes 0..31)
        const int nst = m >> 3;
        for (int i = 0; i < nst; i++) {
            int s = __shfl(idx, i * 8 + srow, 64);
            const unsigned char* g = xs8 + (((size_t)(unsigned)s) << 7) + schunk;
            gload16(g, sb + i * 1024);
        }
        asm volatile("s_waitcnt vmcnt(0)" ::: "memory");
        __builtin_amdgcn_sched_barrier(0);
#pragma unroll 2
        for (int j = 0; j < m; j += 4) {
            int r = j + grp;
            unsigned off = ((unsigned)r << 7) | (rbase ^ (((unsigned)r & 7) << 4));
            uint2 v = *(const uint2*)(sb + off);     // ds_read_b64, conflict-free
            fp8x8_add(v, acc);
        }
    }

    float a[8] = {acc[0][0], acc[0][1], acc[1][0], acc[1][1],
                  acc[2][0], acc[2][1], acc[3][0], acc[3][1]};
#pragma unroll
    for (int k = 0; k < 8; k++) {
        a[k] += __shfl_xor(a[k], 16, 64);
        a[k] += __shfl_xor(a[k], 32, 64);
    }

    if (grp == 0) {
        const float d = dinv[n];
        const float4 b0 = ((const float4*)bias)[fl * 2];
        const float4 b1 = ((const float4*)bias)[fl * 2 + 1];
        const float bb[8] = {b0.x, b0.y, b0.z, b0.w, b1.x, b1.y, b1.z, b1.w};
        float v[8];
#pragma unroll
        for (int k = 0; k < 8; k++) {
            v[k] = d * a[k] + bb[k];
            if (do_relu) v[k] = fmaxf(v[k], 0.f);
        }
        uint2 o;
        unsigned d0 = __builtin_amdgcn_cvt_pk_fp8_f32(v[0], v[1], 0u, false);
        o.x = __builtin_amdgcn_cvt_pk_fp8_f32(v[2], v[3], d0, true);
        unsigned d1 = __builtin_amdgcn_cvt_pk_fp8_f32(v[4], v[5], 0u, false);
        o.y = __builtin_amdgcn_cvt_pk_fp8_f32(v[6], v[7], d1, true);
        ((uint2*)out)[(size_t)n * 16 + fl] = o;
    }
}

// ---------------- pool (fp8 input): 8 lane-groups x 32-node serial runs ----------------

__launch_bounds__(256)
__global__ void k_pool(const unsigned char* __restrict__ x3, const int* __restrict__ batch,
                       float* __restrict__ sums, int N) {
    const int t = threadIdx.x;
    const int fq = t & 31;              // feature quad: features 4*fq .. 4*fq+3
    const int sub = t >> 5;             // node lane 0..7
    const int n0 = blockIdx.x * 256 + sub * 32;
    if (n0 >= N) return;
    const int n1 = (n0 + 32 < N) ? n0 + 32 : N;

    f32x4 acc = {0.f, 0.f, 0.f, 0.f};
    int cur = batch[n0];
    for (int n = n0; n < n1; n++) {
        int g = batch[n];
        if (g != cur) {
            float* s = &sums[cur * FDIM + (fq << 2)];
            atomicAdd(s + 0, acc[0]); atomicAdd(s + 1, acc[1]);
            atomicAdd(s + 2, acc[2]); atomicAdd(s + 3, acc[3]);
            acc = (f32x4){0.f, 0.f, 0.f, 0.f};
            cur = g;
        }
        unsigned w = *(const unsigned*)(x3 + ((size_t)n << 7) + (fq << 2));
        f32x2 lo = __builtin_amdgcn_cvt_pk_f32_fp8(w, false);
        f32x2 hi = __builtin_amdgcn_cvt_pk_f32_fp8(w, true);
        acc[0] += lo[0]; acc[1] += lo[1]; acc[2] += hi[0]; acc[3] += hi[1];
    }
    float* s = &sums[cur * FDIM + (fq << 2)];
    atomicAdd(s + 0, acc[0]); atomicAdd(s + 1, acc[1]);
    atomicAdd(s + 2, acc[2]); atomicAdd(s + 3, acc[3]);
}

// ---------------- per-graph mean + MLP + LayerNorm ----------------

__launch_bounds__(128)
__global__ void k_final(const float* __restrict__ sums, const int* __restrict__ batch, int N,
                        const float* __restrict__ Wm1, const float* __restrict__ bm1,
                        const float* __restrict__ Wm2, const float* __restrict__ bm2,
                        const float* __restrict__ ln_g, const float* __restrict__ ln_b,
                        float* __restrict__ out) {
    const int g = blockIdx.x;
    const int t = threadIdx.x;

    int lo = 0, hi = N;
    while (lo < hi) { int mid = (lo + hi) >> 1; if (batch[mid] < g) lo = mid + 1; else hi = mid; }
    int lo2 = lo, hi2 = N;
    while (lo2 < hi2) { int mid = (lo2 + hi2) >> 1; if (batch[mid] < g + 1) lo2 = mid + 1; else hi2 = mid; }
    float cnt = (float)(lo2 - lo);

    float gl = sums[g * FDIM + t] / fmaxf(cnt, 1.0f);

    __shared__ float gbuf[FDIM];
    __shared__ float hbuf[FDIM];
    __shared__ float wsum[4];
    gbuf[t] = gl;
    __syncthreads();

    float h = bm1[t];
#pragma unroll 8
    for (int k = 0; k < FDIM; k++) h += gbuf[k] * Wm1[k * FDIM + t];
    h = fmaxf(h, 0.f);
    hbuf[t] = h;
    __syncthreads();

    float y = bm2[t];
#pragma unroll 8
    for (int k = 0; k < FDIM; k++) y += hbuf[k] * Wm2[k * FDIM + t];

    float s = y, s2 = y * y;
#pragma unroll
    for (int off = 32; off > 0; off >>= 1) {
        s += __shfl_down(s, off, 64);
        s2 += __shfl_down(s2, off, 64);
    }
    if ((t & 63) == 0) { wsum[t >> 6] = s; wsum[2 + (t >> 6)] = s2; }
    __syncthreads();
    float sum = wsum[0] + wsum[1];
    float sumsq = wsum[2] + wsum[3];
    float mu = sum * (1.0f / FDIM);
    float var = sumsq * (1.0f / FDIM) - mu * mu;
    float r = rsqrtf(var + LN_EPS);
    out[g * FDIM + t] = (y - mu) * r * ln_g[t] + ln_b[t];
}

// ---------------- launch ----------------

extern "C" void kernel_launch(void* const* d_in, const int* in_sizes, int n_in,
                              void* d_out, int out_size, void* d_ws, size_t ws_size,
                              hipStream_t stream) {
    const float* x_in  = (const float*)d_in[0];
    const int*   eidx  = (const int*)d_in[1];
    const int*   batch = (const int*)d_in[2];
    const float* W1 = (const float*)d_in[3];
    const float* b1 = (const float*)d_in[4];
    const float* W2 = (const float*)d_in[5];
    const float* b2 = (const float*)d_in[6];
    const float* W3 = (const float*)d_in[7];
    const float* b3 = (const float*)d_in[8];
    const float* Wm1 = (const float*)d_in[9];
    const float* bm1 = (const float*)d_in[10];
    const float* Wm2 = (const float*)d_in[11];
    const float* bm2 = (const float*)d_in[12];
    const float* ln_g = (const float*)d_in[13];
    const float* ln_b = (const float*)d_in[14];
    float* out = (float*)d_out;

    const int N = in_sizes[0] / FDIM;   // 100000
    const int E = in_sizes[1] / 2;      // 1600000
    const int G = out_size / FDIM;      // 64

    const int* src = eidx;
    const int* dst = eidx + E;

    const int nbkt = (N + BKT_NODES - 1) >> NBKT_SHIFT;        // 391

    // workspace layout (B0q/B1q have one extra zero row at index N)
    char* p = (char*)d_ws;
    unsigned* bktA = (unsigned*)p;    p += (size_t)nbkt * BKT_CAP * 4;   // 12.8 MB (packed)
    unsigned char* B0q = (unsigned char*)p; p += (size_t)(N + 1) * FDIM; // 12.8 MB (fp8 xs)
    unsigned char* B1q = (unsigned char*)p; p += (size_t)(N + 1) * FDIM; // 12.8 MB (fp8 agg)
    int* csr_src = (int*)p;           p += (size_t)nbkt * BKT_CAP * 4;   // 12.8 MB
    int2* rowinfo = (int2*)p;         p += (size_t)N * 8;
    float* dinv = (float*)p;          p += (size_t)N * 4;
    ushort* Wt_b = (ushort*)p;        p += 16384 * 2;
    unsigned char* Wt8 = (unsigned char*)p; p += 2 * 16384;
    float* gsums = (float*)p;         p += (size_t)G * FDIM * 4;
    int* bcur = (int*)p;              p += MAXBKT * 4;

    const int TPB = 256;
    dim3 blk(TPB);
    dim3 gAgg((N + 3) / 4);
    dim3 gTile((N + 127) / 128);
    const int nEb = (E + 4095) / 4096;

    // ---- prep (also zeroes gsums/bcur/zero-rows) + build ----
    k_prep_w<<<dim3(192), blk, 0, stream>>>(W1, W2, W3, Wt_b, Wt8, gsums, bcur, B0q, B1q, N);
    k_bkt_scatter<<<dim3(nEb), blk, 0, stream>>>(src, dst, bcur, bktA, E, nbkt);
    k_build<<<dim3(nbkt), dim3(512), 0, stream>>>(bktA, bcur, rowinfo, dinv, csr_src, N);

    // ---- layer 1 (fp32 input, bf16 MFMA) ----
    k_gemm_f32<<<gTile, blk, 0, stream>>>(x_in, Wt_b, dinv, B0q, N);
    k_aggregate<<<gAgg, blk, 0, stream>>>(B0q, rowinfo, csr_src, dinv, b1, B1q, N, 1);

    // ---- layer 2 (fp8 MFMA) ----
    k_gemm_fp8<<<gTile, blk, 0, stream>>>(B1q, Wt8, dinv, B0q, N);
    k_aggregate<<<gAgg, blk, 0, stream>>>(B0q, rowinfo, csr_src, dinv, b2, B1q, N, 1);

    // ---- layer 3 (fp8 MFMA, no relu) ----
    k_gemm_fp8<<<gTile, blk, 0, stream>>>(B1q, Wt8 + 16384, dinv, B0q, N);
    k_aggregate<<<gAgg, blk, 0, stream>>>(B0q, rowinfo, csr_src, dinv, b3, B1q, N, 0);

    // ---- pool + MLP + LN ----
    k_pool<<<dim3((N + 255) / 256), blk, 0, stream>>>(B1q, batch, gsums, N);
    k_final<<<dim3(G), dim3(FDIM), 0, stream>>>(gsums, batch, N, Wm1, bm1, Wm2, bm2,
                                                ln_g, ln_b, out);
}